// Round 11
// baseline (198.863 us; speedup 1.0000x reference)
//
#include <hip/hip_runtime.h>
#include <math.h>

#define Bb 64
#define Qn 512
#define Kn 512
#define Cn 256
#define Hn 8
#define HDn 32
#define OUTn 256

typedef __bf16 bf16_t;
typedef __attribute__((ext_vector_type(4))) __bf16 bf16x4;
typedef __attribute__((ext_vector_type(8))) __bf16 bf16x8;
typedef __attribute__((ext_vector_type(4))) float f32x4;
typedef __attribute__((ext_vector_type(4))) unsigned int u32x4;

__device__ inline bf16_t tob(float f) {
    unsigned int u = __float_as_uint(f);
    u += 0x7fff + ((u >> 16) & 1);   // RNE
    unsigned short s = (unsigned short)(u >> 16);
    return __builtin_bit_cast(bf16_t, s);
}

// async global->LDS, 16B per lane; LDS dest = wave-uniform base + lane*16
__device__ inline void gl_lds16(const void* g, void* l) {
    __builtin_amdgcn_global_load_lds(
        (const __attribute__((address_space(1))) unsigned int*)g,
        (__attribute__((address_space(3))) unsigned int*)l, 16, 0, 0);
}

// ---------------- weight prep: cast to bf16, MFMA-fragment-tiled ----------
// weights stored in the exact B-fragment order proj/outproj consume:
//   element (n, k) -> wt[ ((n>>4)*8 + (k>>5))*512 + lane*8 + (k&7) ],
//   lane = ((k>>3)&3)*16 + (n&15).
__global__ __launch_bounds__(256) void prep_weights(
    const float* __restrict__ qw, const float* __restrict__ kw,
    const float* __restrict__ vw, const float* __restrict__ gw,
    const float* __restrict__ ow,
    bf16_t* __restrict__ wtq, bf16_t* __restrict__ wtk,
    bf16_t* __restrict__ wtv, bf16_t* __restrict__ wtg,
    bf16_t* __restrict__ wto)
{
    int tid = blockIdx.x * 256 + threadIdx.x;   // 0 .. 5*65536-1
    int mat = tid >> 16;
    int rem = tid & 65535;
    int a = rem >> 8;    // source row (k dim)
    int n = rem & 255;   // source col (n dim)
    const float* src = mat == 0 ? qw : mat == 1 ? kw : mat == 2 ? vw : mat == 3 ? gw : ow;
    bf16_t* dst = mat == 0 ? wtq : mat == 1 ? wtk : mat == 2 ? wtv : mat == 3 ? wtg : wto;
    int nb = n >> 4, kb = a >> 5, rg = (a >> 3) & 3, e = a & 7, nl = n & 15;
    size_t idx = (((size_t)(nb * 8 + kb) * 64) + rg * 16 + nl) * 8 + e;
    dst[idx] = tob(src[a * 256 + n]);
}

// ---------------- bias tiling: rearrange to MFMA-fragment layout ----------
// btile[b][q16][c][t][lane][r] = bias[b][q16*16+(lane&15)][c*64+t*16+(lane>>4)*4+r]
// ntile[h][q16][c][t][lane][r] = nbias[h][same][same]
__global__ __launch_bounds__(256) void prep_bias(
    const float* __restrict__ bias, const float* __restrict__ nbias,
    float* __restrict__ btile, float* __restrict__ ntile)
{
    size_t vid = (size_t)blockIdx.x * 256 + threadIdx.x;   // one f32x4 each
    const size_t NB = (size_t)64 * 65536;                  // bias vec4 count
    int lane, t, c, q16;
    if (vid < NB) {
        lane = vid & 63; t = (vid >> 6) & 3; c = (vid >> 8) & 7; q16 = (vid >> 11) & 31;
        int b = vid >> 16;
        int row = q16 * 16 + (lane & 15);
        int col = c * 64 + t * 16 + (lane >> 4) * 4;
        f32x4 v = *reinterpret_cast<const f32x4*>(bias + ((size_t)b * Qn + row) * Kn + col);
        *reinterpret_cast<f32x4*>(btile + vid * 4) = v;
    } else {
        size_t nv = vid - NB;                              // 8*65536 vec4
        lane = nv & 63; t = (nv >> 6) & 3; c = (nv >> 8) & 7; q16 = (nv >> 11) & 31;
        int h = nv >> 16;
        int row = q16 * 16 + (lane & 15);
        int col = c * 64 + t * 16 + (lane >> 4) * 4;
        f32x4 v = *reinterpret_cast<const f32x4*>(nbias + ((size_t)h * Qn + row) * Kn + col);
        *reinterpret_cast<f32x4*>(ntile + nv * 4) = v;
    }
}

// ---------------- projections ----------------
// R11: occupancy-first rebuild. R9/R10 exonerated store- and load-scatter
// (96us, all patterns clean, occupancy 23%, VGPR 72 > the 64 cliff).
// New shape: 256-thd block = 32 m-rows x ONE matrix (grid 1024 x 4);
// wave tile 32x64 -> acc[2][4] = 32 VGPR, live state ~56;
// __launch_bounds__(256,8) forces <=64 VGPR -> 8 waves/SIMD eligible.
// LDS 20.6KB (A-tile 32x264 + reused epilogue scratch) -> 7 blocks/CU.
// R1<->R6 calibration: 2x occupancy ~= 1.4-1.7x on this latency profile.
// v output (mat==2) uses swapped MFMA; kk bit-perm folded into scratch
// column; all global stores remain full-64B-line segments (R9).
#define ALDS_STRIDE 264   // 256 + 8 pad
__global__ __launch_bounds__(256, 8) void proj_kernel(
    const float* __restrict__ qdata, const float* __restrict__ mdata,
    const bf16_t* __restrict__ wtq, const bf16_t* __restrict__ wtk,
    const bf16_t* __restrict__ wtv, const bf16_t* __restrict__ wtg,
    const float* __restrict__ gating_b,
    bf16_t* __restrict__ qb, bf16_t* __restrict__ kb,
    bf16_t* __restrict__ vTb, bf16_t* __restrict__ gateb)
{
    __shared__ __align__(16) bf16_t smem[10304];   // A-tile 8448 / scratch 4x2576
    bf16_t* alds = smem;
    const int mat = blockIdx.y;           // 0=q, 1=k, 2=v, 3=gate
    const int m0 = blockIdx.x * 32;
    const int tid = threadIdx.x;
    const int lane = tid & 63;
    const int w = tid >> 6;               // wave 0..3
    const int ncb = w * 64;
    const int c15 = lane & 15;
    const int rgrp = lane >> 4;
    const int kof = rgrp * 8;
    const float* X = (mat == 0 || mat == 3) ? qdata : mdata;
    const bf16_t* Wt = mat == 0 ? wtq : mat == 1 ? wtk : mat == 2 ? wtv : wtg;
    const bool vout = (mat == 2);

    // ---- stage A: 32 rows x 256 f32 -> bf16 LDS (cvt_pk + b64 writes) ----
    #pragma unroll
    for (int i = 0; i < 8; i++) {
        int u = tid + i * 256;            // 2048 f32x4 units
        int row = u >> 6;
        int c4 = u & 63;
        f32x4 a4 = *reinterpret_cast<const f32x4*>(X + (size_t)(m0 + row) * 256 + c4 * 4);
        unsigned int p0, p1;
        asm("v_cvt_pk_bf16_f32 %0, %1, %2" : "=v"(p0) : "v"(a4[0]), "v"(a4[1]));
        asm("v_cvt_pk_bf16_f32 %0, %1, %2" : "=v"(p1) : "v"(a4[2]), "v"(a4[3]));
        unsigned long long pk = ((unsigned long long)p1 << 32) | p0;
        *reinterpret_cast<unsigned long long*>(&alds[row * ALDS_STRIDE + c4 * 4]) = pk;
    }
    __syncthreads();

    const bf16_t* wbase = Wt + (size_t)(ncb >> 4) * 8 * 512 + lane * 8;
    f32x4 acc[2][4] = {};
    #pragma unroll 1
    for (int kc = 0; kc < 8; kc++) {
        bf16x8 am[2], bn[4];
        #pragma unroll
        for (int i = 0; i < 2; i++)
            am[i] = *reinterpret_cast<const bf16x8*>(&alds[(i * 16 + c15) * ALDS_STRIDE + kc * 32 + kof]);
        #pragma unroll
        for (int j = 0; j < 4; j++)
            bn[j] = *reinterpret_cast<const bf16x8*>(wbase + ((size_t)j * 8 + kc) * 512);
        #pragma unroll
        for (int i = 0; i < 2; i++)
            #pragma unroll
            for (int j = 0; j < 4; j++) {
                if (vout)
                    acc[i][j] = __builtin_amdgcn_mfma_f32_16x16x32_bf16(bn[j], am[i], acc[i][j], 0, 0, 0);
                else
                    acc[i][j] = __builtin_amdgcn_mfma_f32_16x16x32_bf16(am[i], bn[j], acc[i][j], 0, 0, 0);
            }
    }

    __syncthreads();                      // A-tile reads done; reuse as scratch
    bf16_t* scr = smem + w * 2576;        // per-wave slice, 16B-aligned

    const float scale = 0.17677669529663687f * 1.4426950408889634f;  // /sqrt32 * log2e
    const int hbase = ncb >> 5;           // first h of this wave's 64 n-cols
    const int posbase = m0 & 511;
    const int b = m0 >> 9;

    if (!vout) {
        bf16_t* dst = mat == 0 ? qb : mat == 1 ? kb : gateb;
        // stage: scr[m 32][n 64], stride 72 (144B rows, 16B-aligned)
        #pragma unroll
        for (int i = 0; i < 2; i++)
            #pragma unroll
            for (int j = 0; j < 4; j++) {
                int n_loc = j * 16 + c15;
                #pragma unroll
                for (int r = 0; r < 4; r++) {
                    float v = acc[i][j][r];
                    if (mat == 0) v *= scale;
                    else if (mat == 3) v = 1.f / (1.f + __expf(-(v + gating_b[ncb + n_loc])));
                    scr[(i * 16 + rgrp * 4 + r) * 72 + n_loc] = tob(v);
                }
            }
        asm volatile("" ::: "memory");
        // readback: 8 rows/instr x 16B/lane, full 64B segments
        #pragma unroll
        for (int u = 0; u < 4; u++) {
            int row = u * 8 + (lane >> 3);
            int nof = (lane & 7) * 8;
            bf16x8 val = *reinterpret_cast<const bf16x8*>(&scr[row * 72 + nof]);
            int hh = hbase + (nof >> 5);
            int d = nof & 31;
            int pos = posbase + row;
            *reinterpret_cast<bf16x8*>(dst + (((size_t)(b * Hn + hh) * Qn + pos) << 5) + d) = val;
        }
    } else {
        // transposed acc: lanes index m (c15), regs index n (rgrp*4+r).
        // kk perm on low 5 bits folded into scratch column (posbase % 32 == 0).
        #pragma unroll
        for (int i = 0; i < 2; i++) {
            int col = (((c15 >> 3) & 1) << 4) | (((c15 >> 2) & 1) << 3) | (i << 2) | (c15 & 3);
            #pragma unroll
            for (int j = 0; j < 4; j++)
                #pragma unroll
                for (int r = 0; r < 4; r++)
                    scr[(j * 16 + rgrp * 4 + r) * 40 + col] = tob(acc[i][j][r]);
        }
        asm volatile("" ::: "memory");
        // readback: scr[n 64][kk 32], 16 rows/instr x 16B/lane, 64B segments
        #pragma unroll
        for (int u = 0; u < 4; u++) {
            int n_loc = u * 16 + (lane >> 2);
            int mof = (lane & 3) * 8;
            bf16x8 val = *reinterpret_cast<const bf16x8*>(&scr[n_loc * 40 + mof]);
            int hh = hbase + (n_loc >> 5);
            int d = n_loc & 31;
            *reinterpret_cast<bf16x8*>(vTb + ((size_t)(b * Hn + hh) * HDn + d) * Kn
                                       + posbase + mof) = val;
        }
    }
}

// ---------------- fused attention, TILED-BIAS (R8, unchanged) -------------
// bias/nbias pre-tiled to fragment layout -> 8 coalesced dwordx4 per chunk
// straight to registers. LDS = 16KB kv dbuf only. Counted vmcnt(8): at the
// wait, outstanding = stage(c)[2 oldest] + bias(c)[8 newer].
__global__ __launch_bounds__(256) void attn_kernel(
    const bf16_t* __restrict__ qb, const bf16_t* __restrict__ kb,
    const bf16_t* __restrict__ vTb, const bf16_t* __restrict__ gateb,
    const float* __restrict__ btile, const float* __restrict__ ntile,
    bf16_t* __restrict__ wab)
{
    __shared__ __align__(16) char kvlds[2][8192];    // [buf][K 4KB | V 4KB]
    const int p = blockIdx.x;
    const int qt = p & 7;
    const int h = (p >> 3) & 7;
    const int b = p >> 6;
    const int lane = threadIdx.x & 63;
    const int wv = threadIdx.x >> 6;
    const int q0 = qt * 64 + wv * 16;
    const int q16 = qt * 4 + wv;
    const int c15 = lane & 15;
    const int rgrp = lane >> 4;
    const int kof = rgrp * 8;

    const bf16_t* qbase = qb + (size_t)(b * Hn + h) * Qn * HDn;
    const bf16_t* kbase = kb + (size_t)(b * Hn + h) * Kn * HDn;
    const bf16_t* vbase = vTb + (size_t)(b * Hn + h) * HDn * Kn;
    const float* btb = btile + (((size_t)b * 32 + q16) << 13) + lane * 4;   // 8192 f/q16
    const float* ntb = ntile + (((size_t)h * 32 + q16) << 13) + lane * 4;

    // staging lane geometry (constant per thread)
    const int krw = (wv << 4) + (lane >> 2);        // K row 0..63
    const int kcb = (lane & 3) << 4;                // K col byte
    const int vrw = (wv << 3) + (lane >> 3);        // V row 0..31
    const int vcb = (lane & 7) << 4;                // V col byte
    const size_t ksrc0 = ((size_t)krw << 6) + (size_t)(kcb ^ ((krw & 3) << 4));
    const size_t vsrc0 = ((size_t)vrw << 10) + (size_t)(vcb ^ ((vrw & 7) << 4));

    bf16x8 aq = *reinterpret_cast<const bf16x8*>(qbase + (q0 + c15) * HDn + kof);

    const float NML = -12.f * 1.4426950408889634f;   // -M*log2e, folded into QK^T C
    const float LOG2E = 1.4426950408889634f;
    const f32x4 zML = {NML, NML, NML, NML};
    f32x4 o[2] = {};
    f32x4 lsv = {0.f, 0.f, 0.f, 0.f};

    // ---- prologue: stage chunk 0 -> LDS buf 0 ----
    gl_lds16((const char*)kbase + ksrc0, (char*)kvlds[0] + wv * 1024);
    gl_lds16((const char*)vbase + vsrc0, (char*)kvlds[0] + 4096 + wv * 1024);

    #pragma unroll 1
    for (int c = 0; c < 8; c++) {         // 8 chunks of 64 k-cols
        const int pb = c & 1;
        // ---- bias/nbias tiled loads: 8 coalesced dwordx4 (newest VMEM) ----
        f32x4 bt[4], nt_[4];
        #pragma unroll
        for (int t = 0; t < 4; t++) {
            bt[t]  = *reinterpret_cast<const f32x4*>(btb + c * 1024 + t * 256);
            nt_[t] = *reinterpret_cast<const f32x4*>(ntb + c * 1024 + t * 256);
        }
        // ---- counted drain: kill stage(c) [2 oldest], keep bias [8] ----
        __builtin_amdgcn_sched_barrier(0);
        asm volatile("s_waitcnt vmcnt(8)" ::: "memory");
        __builtin_amdgcn_s_barrier();
        __builtin_amdgcn_sched_barrier(0);
        // ---- issue stage(c+1) into the other buffer (safe: post-barrier) --
        if (c < 7) {
            char* dstb = (char*)kvlds[pb ^ 1] + wv * 1024;
            gl_lds16((const char*)kbase + (size_t)((c + 1) << 12) + ksrc0, dstb);
            gl_lds16((const char*)vbase + (size_t)((c + 1) << 7) + vsrc0, dstb + 4096);
        }
        // ---- QK^T from LDS K tile (swizzled read) ----
        const char* kl = (const char*)kvlds[pb];
        f32x4 sc[4];
        #pragma unroll
        for (int t = 0; t < 4; t++) {
            int kr = t * 16 + c15;
            bf16x8 kf = *reinterpret_cast<const bf16x8*>(kl + (kr << 6) + ((rgrp << 4) ^ ((kr & 3) << 4)));
            sc[t] = __builtin_amdgcn_mfma_f32_16x16x32_bf16(kf, aq, zML, 0, 0, 0);
        }
        // ---- softmax: e = exp2(fma(bb, L, sc)); pack P via cvt_pk ----
        f32x4 es[4];
        #pragma unroll
        for (int t = 0; t < 4; t++) {
            f32x4 bb = bt[t] + nt_[t];
            #pragma unroll
            for (int r = 0; r < 4; r++)
                es[t][r] = __builtin_amdgcn_exp2f(fmaf(bb[r], LOG2E, sc[t][r]));
            lsv += es[t];
        }
        unsigned int pw[8];
        #pragma unroll
        for (int t = 0; t < 4; t++) {
            asm("v_cvt_pk_bf16_f32 %0, %1, %2" : "=v"(pw[t * 2 + 0]) : "v"(es[t][0]), "v"(es[t][1]));
            asm("v_cvt_pk_bf16_f32 %0, %1, %2" : "=v"(pw[t * 2 + 1]) : "v"(es[t][2]), "v"(es[t][3]));
        }
        u32x4 a0 = {pw[0], pw[1], pw[2], pw[3]};
        u32x4 a1 = {pw[4], pw[5], pw[6], pw[7]};
        bf16x8 pa0 = __builtin_bit_cast(bf16x8, a0);
        bf16x8 pa1 = __builtin_bit_cast(bf16x8, a1);
        // ---- PV from LDS V tile (swizzled read), P in-register ----
        #pragma unroll
        for (int sub = 0; sub < 2; sub++) {
            bf16x8 ap = sub == 0 ? pa0 : pa1;
            #pragma unroll
            for (int nt = 0; nt < 2; nt++) {
                int vr = nt * 16 + c15;
                bf16x8 bv = *reinterpret_cast<const bf16x8*>(kl + 4096 + (vr << 7)
                                + (((sub << 6) | (rgrp << 4)) ^ ((vr & 7) << 4)));
                o[nt] = __builtin_amdgcn_mfma_f32_16x16x32_bf16(ap, bv, o[nt], 0, 0, 0);
            }
        }
    }

    float lsum = (lsv[0] + lsv[1]) + (lsv[2] + lsv[3]);
    lsum += __shfl_xor(lsum, 16, 64);
    lsum += __shfl_xor(lsum, 32, 64);
    float linv[4];
    #pragma unroll
    for (int r = 0; r < 4; r++)
        linv[r] = 1.f / __shfl(lsum, rgrp * 4 + r, 64);

    // epilogue: normalize, gate, store wa as bf16 [B,Q,H*HD]
    const bf16_t* gptr = gateb + (size_t)(b * Hn + h) * Qn * HDn;
    bf16_t* wptr = wab + (size_t)b * Qn * 256;
    const int qg = q0 + rgrp * 4;
    #pragma unroll
    for (int nt = 0; nt < 2; nt++) {
        int d = nt * 16 + c15;
        #pragma unroll
        for (int r = 0; r < 4; r++) {
            float g = (float)gptr[(qg + r) * HDn + d];
            wptr[(qg + r) * 256 + h * 32 + d] = tob(o[nt][r] * linv[r] * g);
        }
    }
}

// ---------------- output projection + bias ----------------
__global__ __launch_bounds__(256) void outproj_kernel(
    const bf16_t* __restrict__ wab, const bf16_t* __restrict__ wto,
    const float* __restrict__ outb, float* __restrict__ out)
{
    __shared__ bf16_t alds[64 * ALDS_STRIDE];
    const int m0 = blockIdx.x * 64;
    const int tid = threadIdx.x;
    const int lane = tid & 63;
    const int w = tid >> 6;
    const int ncb = w * 64;
    const int c15 = lane & 15;
    const int rgrp = lane >> 4;
    const int kof = rgrp * 8;

    #pragma unroll
    for (int i = 0; i < 8; i++) {
        int u = tid + i * 256;
        int row = u >> 5;
        int c16 = u & 31;
        bf16x8 a8 = *reinterpret_cast<const bf16x8*>(wab + (size_t)(m0 + row) * 256 + c16 * 8);
        *reinterpret_cast<bf16x8*>(&alds[row * ALDS_STRIDE + c16 * 8]) = a8;
    }
    __syncthreads();

    const bf16_t* wbase = wto + (size_t)(ncb >> 4) * 8 * 512 + lane * 8;
    f32x4 acc[4][4] = {};
    #pragma unroll
    for (int kc = 0; kc < 8; kc++) {
        bf16x8 am[4], bn[4];
        #pragma unroll
        for (int i = 0; i < 4; i++)
            am[i] = *reinterpret_cast<const bf16x8*>(&alds[(i * 16 + c15) * ALDS_STRIDE + kc * 32 + kof]);
        #pragma unroll
        for (int j = 0; j < 4; j++)
            bn[j] = *reinterpret_cast<const bf16x8*>(wbase + ((size_t)j * 8 + kc) * 512);
        #pragma unroll
        for (int i = 0; i < 4; i++)
            #pragma unroll
            for (int j = 0; j < 4; j++)
                acc[i][j] = __builtin_amdgcn_mfma_f32_16x16x32_bf16(am[i], bn[j], acc[i][j], 0, 0, 0);
    }

    #pragma unroll
    for (int j = 0; j < 4; j++) {
        int n = ncb + j * 16 + c15;
        float ob = outb[n];
        #pragma unroll
        for (int i = 0; i < 4; i++) {
            #pragma unroll
            for (int r = 0; r < 4; r++) {
                int m = m0 + i * 16 + rgrp * 4 + r;
                out[(size_t)m * 256 + n] = acc[i][j][r] + ob;
            }
        }
    }
}

extern "C" void kernel_launch(void* const* d_in, const int* in_sizes, int n_in,
                              void* d_out, int out_size, void* d_ws, size_t ws_size,
                              hipStream_t stream) {
    const float* q_data = (const float*)d_in[0];
    const float* m_data = (const float*)d_in[1];
    const float* bias = (const float*)d_in[2];
    const float* nbias = (const float*)d_in[3];
    const float* query_w = (const float*)d_in[4];
    const float* key_w = (const float*)d_in[5];
    const float* value_w = (const float*)d_in[6];
    const float* gating_w = (const float*)d_in[7];
    const float* gating_b = (const float*)d_in[8];
    const float* output_w = (const float*)d_in[9];
    const float* output_b = (const float*)d_in[10];
    float* out = (float*)d_out;

    char* ws = (char*)d_ws;
    const size_t WT = 256 * 256 * sizeof(bf16_t);
    const size_t PROJ = (size_t)Bb * Hn * Qn * HDn;      // bf16 elems
    bf16_t* wtq = (bf16_t*)(ws);
    bf16_t* wtk = (bf16_t*)(ws + WT);
    bf16_t* wtv = (bf16_t*)(ws + 2 * WT);
    bf16_t* wtg = (bf16_t*)(ws + 3 * WT);
    bf16_t* wto = (bf16_t*)(ws + 4 * WT);
    bf16_t* qb = (bf16_t*)(ws + 5 * WT);
    bf16_t* kb = qb + PROJ;
    bf16_t* vtb = kb + PROJ;
    bf16_t* gateb = vtb + PROJ;
    bf16_t* wab = gateb + PROJ;

    const size_t BASE = 5 * WT + 5 * PROJ * sizeof(bf16_t);
    const size_t BT_BYTES = (size_t)64 * 65536 * 16;     // 67.1 MB
    float* btile = (float*)(ws + BASE);
    float* ntile = (float*)(ws + BASE + BT_BYTES);

    prep_weights<<<1280, 256, 0, stream>>>(query_w, key_w, value_w, gating_w, output_w,
                                           wtq, wtk, wtv, wtg, wto);
    prep_bias<<<18432, 256, 0, stream>>>(bias, nbias, btile, ntile);
    proj_kernel<<<dim3(1024, 4), 256, 0, stream>>>(q_data, m_data, wtq, wtk, wtv, wtg,
                                                   gating_b, qb, kb, vtb, gateb);
    attn_kernel<<<4096, 256, 0, stream>>>(qb, kb, vtb, gateb, btile, ntile, wab);
    outproj_kernel<<<512, 256, 0, stream>>>(wab, wto, output_b, out);
}

// Round 12
// 171.562 us; speedup vs baseline: 1.1591x; 1.1591x over previous
//
#include <hip/hip_runtime.h>
#include <math.h>

#define Bb 64
#define Qn 512
#define Kn 512
#define Cn 256
#define Hn 8
#define HDn 32
#define OUTn 256

typedef __bf16 bf16_t;
typedef __attribute__((ext_vector_type(4))) __bf16 bf16x4;
typedef __attribute__((ext_vector_type(8))) __bf16 bf16x8;
typedef __attribute__((ext_vector_type(4))) float f32x4;
typedef __attribute__((ext_vector_type(4))) unsigned int u32x4;

__device__ inline bf16_t tob(float f) {
    unsigned int u = __float_as_uint(f);
    u += 0x7fff + ((u >> 16) & 1);   // RNE
    unsigned short s = (unsigned short)(u >> 16);
    return __builtin_bit_cast(bf16_t, s);
}

// async global->LDS, 16B per lane; LDS dest = wave-uniform base + lane*16
__device__ inline void gl_lds16(const void* g, void* l) {
    __builtin_amdgcn_global_load_lds(
        (const __attribute__((address_space(1))) unsigned int*)g,
        (__attribute__((address_space(3))) unsigned int*)l, 16, 0, 0);
}

// ---------------- weight prep: cast to bf16, MFMA-fragment-tiled ----------
// weights stored in the exact B-fragment order proj/outproj consume:
//   element (n, k) -> wt[ ((n>>4)*8 + (k>>5))*512 + lane*8 + (k&7) ],
//   lane = ((k>>3)&3)*16 + (n&15).
__global__ __launch_bounds__(256) void prep_weights(
    const float* __restrict__ qw, const float* __restrict__ kw,
    const float* __restrict__ vw, const float* __restrict__ gw,
    const float* __restrict__ ow,
    bf16_t* __restrict__ wtq, bf16_t* __restrict__ wtk,
    bf16_t* __restrict__ wtv, bf16_t* __restrict__ wtg,
    bf16_t* __restrict__ wto)
{
    int tid = blockIdx.x * 256 + threadIdx.x;   // 0 .. 5*65536-1
    int mat = tid >> 16;
    int rem = tid & 65535;
    int a = rem >> 8;    // source row (k dim)
    int n = rem & 255;   // source col (n dim)
    const float* src = mat == 0 ? qw : mat == 1 ? kw : mat == 2 ? vw : mat == 3 ? gw : ow;
    bf16_t* dst = mat == 0 ? wtq : mat == 1 ? wtk : mat == 2 ? wtv : mat == 3 ? wtg : wto;
    int nb = n >> 4, kb = a >> 5, rg = (a >> 3) & 3, e = a & 7, nl = n & 15;
    size_t idx = (((size_t)(nb * 8 + kb) * 64) + rg * 16 + nl) * 8 + e;
    dst[idx] = tob(src[a * 256 + n]);
}

// ---------------- bias tiling via LDS transpose (R12) ---------------------
// R12: old prep_bias READ side was the R2-proven scatter (lane->row 2KB
// stride, 16 segments/instr, 25% line use). New: block = one (b|h, q16)
// 16x512 tile; coalesced row reads -> LDS (stride 516 f32, 16B-aligned)
// -> fragment-order readback -> coalesced writes. Both sides full-line.
// btile[b][q16][c][t][lane][r] = bias[b][q16*16+(lane&15)][c*64+t*16+(lane>>4)*4+r]
__global__ __launch_bounds__(256) void prep_bias(
    const float* __restrict__ bias, const float* __restrict__ nbias,
    float* __restrict__ btile, float* __restrict__ ntile)
{
    __shared__ float tl[16 * 516];        // 33KB: 16 rows x (512+4)
    const int blk = blockIdx.x;
    const bool isn = blk >= 2048;
    const int id2 = isn ? blk - 2048 : blk;   // (b or h)*32 + q16
    const int q16 = id2 & 31;
    const int bh = id2 >> 5;
    const int tid = threadIdx.x;
    const float* src = (isn ? nbias : bias) + ((size_t)bh * Qn + q16 * 16) * Kn;
    float* dst = (isn ? ntile : btile) + ((size_t)id2 << 13);

    #pragma unroll
    for (int i = 0; i < 8; i++) {
        int u = tid + i * 256;            // 2048 f32x4 units
        int row = u >> 7;                 // 0..15
        int c4 = u & 127;                 // col/4
        f32x4 v = *reinterpret_cast<const f32x4*>(src + (size_t)row * Kn + c4 * 4);
        *reinterpret_cast<f32x4*>(&tl[row * 516 + c4 * 4]) = v;
    }
    __syncthreads();
    #pragma unroll
    for (int i = 0; i < 8; i++) {
        int u = tid + i * 256;            // out vec4 index within tile
        int lane = u & 63;
        int t = (u >> 6) & 3;
        int c = u >> 8;
        int row = lane & 15;
        int col = c * 64 + t * 16 + (lane >> 4) * 4;
        f32x4 v = *reinterpret_cast<const f32x4*>(&tl[row * 516 + col]);
        *reinterpret_cast<f32x4*>(dst + (size_t)u * 4) = v;
    }
}

// ---------------- projections (R10 version — measured best, 96us) ---------
// v is stored with a permuted k-axis so attention's PV step can consume P
// directly from the QK^T accumulator layout (no LDS transpose):
//   vbuf[d][kk] = V[pos][d],  kk = perm^-1(pos),
//   perm^-1 on low 5 bits: kk = p3<<4 | p2<<3 | p4<<2 | p1<<1 | p0.
// R9: epilogue restaged through LDS -> fully coalesced 16B stores.
// R10: B-fragments read from the tiled weight layout (1 contiguous 1KB
// line per wave-instr); A-staging via v_cvt_pk_bf16_f32 + b64 writes.
// R11 NOTE: halving the tile to force VGPR<=64 DOUBLED occupancy (23->44%)
// with ZERO speedup and +31MB FETCH -> occupancy is NOT proj's binding
// resource; this 64x64-tile version is the measured optimum.
#define ALDS_STRIDE 264   // 256 + 8 pad
__global__ __launch_bounds__(512) void proj_kernel(
    const float* __restrict__ qdata, const float* __restrict__ mdata,
    const bf16_t* __restrict__ wtq, const bf16_t* __restrict__ wtk,
    const bf16_t* __restrict__ wtv, const bf16_t* __restrict__ wtg,
    const float* __restrict__ gating_b,
    bf16_t* __restrict__ qb, bf16_t* __restrict__ kb,
    bf16_t* __restrict__ vTb, bf16_t* __restrict__ gateb)
{
    __shared__ __align__(16) bf16_t smem[20480];   // A-tile (16896) / scratch (8x2560)
    bf16_t* alds = smem;
    const int side = blockIdx.y;          // 0: q_data, 1: m_data
    const int m0 = blockIdx.x * 64;
    const int tid = threadIdx.x;
    const int lane = tid & 63;
    const int w = tid >> 6;               // wave 0..7
    const int ch = w >> 2;                // 0: q|k, 1: gate|v
    const int ncb = (w & 3) * 64;
    const int c15 = lane & 15;
    const int rgrp = lane >> 4;
    const int kof = rgrp * 8;
    const float* X = side ? mdata : qdata;
    const bf16_t* Wt = side == 0 ? (ch == 0 ? wtq : wtg) : (ch == 0 ? wtk : wtv);
    const bool vout = (side == 1) && (ch == 1);

    #pragma unroll
    for (int i = 0; i < 8; i++) {
        int u = tid + i * 512;            // 4096 f32x4 units
        int row = u >> 6;
        int c4 = u & 63;
        f32x4 a4 = *reinterpret_cast<const f32x4*>(X + (size_t)(m0 + row) * 256 + c4 * 4);
        unsigned int p0, p1;
        asm("v_cvt_pk_bf16_f32 %0, %1, %2" : "=v"(p0) : "v"(a4[0]), "v"(a4[1]));
        asm("v_cvt_pk_bf16_f32 %0, %1, %2" : "=v"(p1) : "v"(a4[2]), "v"(a4[3]));
        unsigned long long pk = ((unsigned long long)p1 << 32) | p0;
        *reinterpret_cast<unsigned long long*>(&alds[row * ALDS_STRIDE + c4 * 4]) = pk;
    }
    __syncthreads();

    const bf16_t* wbase = Wt + (size_t)(ncb >> 4) * 8 * 512 + lane * 8;
    f32x4 acc[4][4] = {};
    #pragma unroll
    for (int kc = 0; kc < 8; kc++) {
        bf16x8 am[4], bn[4];
        #pragma unroll
        for (int i = 0; i < 4; i++)
            am[i] = *reinterpret_cast<const bf16x8*>(&alds[(i * 16 + c15) * ALDS_STRIDE + kc * 32 + kof]);
        #pragma unroll
        for (int j = 0; j < 4; j++)
            bn[j] = *reinterpret_cast<const bf16x8*>(wbase + ((size_t)j * 8 + kc) * 512);
        #pragma unroll
        for (int i = 0; i < 4; i++)
            #pragma unroll
            for (int j = 0; j < 4; j++) {
                if (vout)
                    acc[i][j] = __builtin_amdgcn_mfma_f32_16x16x32_bf16(bn[j], am[i], acc[i][j], 0, 0, 0);
                else
                    acc[i][j] = __builtin_amdgcn_mfma_f32_16x16x32_bf16(am[i], bn[j], acc[i][j], 0, 0, 0);
            }
    }

    __syncthreads();                      // all alds A-tile reads done; reuse as scratch
    bf16_t* scr = smem + w * 2560;        // per-wave slice, 16B-aligned

    // q is pre-scaled by log2(e)/sqrt(32): softmax computes exp2 directly.
    const float scale = 0.17677669529663687f * 1.4426950408889634f;
    const int hbase = ncb >> 5;
    const int posbase = m0 & 511;
    const int b = m0 >> 9;

    if (!vout) {
        bf16_t* dst = side == 0 ? (ch == 0 ? qb : gateb) : kb;
        #pragma unroll
        for (int P = 0; P < 2; P++) {
            // stage 2 i-slices (32 rows x 64 cols) -> scr[row][col], stride 72
            #pragma unroll
            for (int ii = 0; ii < 2; ii++) {
                int i = P * 2 + ii;
                #pragma unroll
                for (int j = 0; j < 4; j++) {
                    int n = ncb + j * 16 + c15;
                    #pragma unroll
                    for (int r = 0; r < 4; r++) {
                        float v = acc[i][j][r];
                        if (side == 0) {
                            if (ch == 0) v *= scale;
                            else v = 1.f / (1.f + __expf(-(v + gating_b[n])));
                        }
                        scr[(ii * 16 + rgrp * 4 + r) * 72 + j * 16 + c15] = tob(v);
                    }
                }
            }
            asm volatile("" ::: "memory");
            // coalesced write-out: 4 iters x 16B/lane, full 64B lines/instr
            #pragma unroll
            for (int v2 = 0; v2 < 4; v2++) {
                int row = v2 * 8 + (lane >> 3);
                int col = (lane & 7) * 8;
                bf16x8 val = *reinterpret_cast<const bf16x8*>(&scr[row * 72 + col]);
                int pos = posbase + P * 32 + row;
                int hh = hbase + (col >> 5);
                int d = col & 31;
                *reinterpret_cast<bf16x8*>(dst + (((size_t)(b * Hn + hh) * Qn + pos) << 5) + d) = val;
            }
            asm volatile("" ::: "memory");   // pass1 writes after pass0 reads
        }
    } else {
        // transposed acc: lanes index m-rows (key positions), regs index n=(h,d)
        // kk perm folded into the LDS WRITE column; readback is stride-1 in kk.
        #pragma unroll
        for (int P = 0; P < 2; P++) {
            #pragma unroll
            for (int ii = 0; ii < 2; ii++) {
                int i = P * 2 + ii;
                int kperm = (((c15 >> 3) & 1) << 4) | (((c15 >> 2) & 1) << 3) | (ii << 2)
                          | (((c15 >> 1) & 1) << 1) | (c15 & 1);
                #pragma unroll
                for (int j = 0; j < 4; j++)
                    #pragma unroll
                    for (int r = 0; r < 4; r++)
                        scr[(j * 16 + rgrp * 4 + r) * 40 + kperm] = tob(acc[i][j][r]);
            }
            asm volatile("" ::: "memory");
            #pragma unroll
            for (int u = 0; u < 4; u++) {
                int nloc = u * 16 + (lane >> 2);
                int koff = (lane & 3) * 8;
                bf16x8 val = *reinterpret_cast<const bf16x8*>(&scr[nloc * 40 + koff]);
                int hh = hbase + (nloc >> 5);
                int d = nloc & 31;
                *reinterpret_cast<bf16x8*>(vTb + ((size_t)(b * Hn + hh) * HDn + d) * Kn
                                           + posbase + P * 32 + koff) = val;
            }
            asm volatile("" ::: "memory");
        }
    }
}

// ---------------- fused attention, TILED-BIAS (R8, unchanged) -------------
// bias/nbias pre-tiled to fragment layout -> 8 coalesced dwordx4 per chunk
// straight to registers. LDS = 16KB kv dbuf only. Counted vmcnt(8): at the
// wait, outstanding = stage(c)[2 oldest] + bias(c)[8 newer].
__global__ __launch_bounds__(256) void attn_kernel(
    const bf16_t* __restrict__ qb, const bf16_t* __restrict__ kb,
    const bf16_t* __restrict__ vTb, const bf16_t* __restrict__ gateb,
    const float* __restrict__ btile, const float* __restrict__ ntile,
    bf16_t* __restrict__ wab)
{
    __shared__ __align__(16) char kvlds[2][8192];    // [buf][K 4KB | V 4KB]
    const int p = blockIdx.x;
    const int qt = p & 7;
    const int h = (p >> 3) & 7;
    const int b = p >> 6;
    const int lane = threadIdx.x & 63;
    const int wv = threadIdx.x >> 6;
    const int q0 = qt * 64 + wv * 16;
    const int q16 = qt * 4 + wv;
    const int c15 = lane & 15;
    const int rgrp = lane >> 4;
    const int kof = rgrp * 8;

    const bf16_t* qbase = qb + (size_t)(b * Hn + h) * Qn * HDn;
    const bf16_t* kbase = kb + (size_t)(b * Hn + h) * Kn * HDn;
    const bf16_t* vbase = vTb + (size_t)(b * Hn + h) * HDn * Kn;
    const float* btb = btile + (((size_t)b * 32 + q16) << 13) + lane * 4;   // 8192 f/q16
    const float* ntb = ntile + (((size_t)h * 32 + q16) << 13) + lane * 4;

    // staging lane geometry (constant per thread)
    const int krw = (wv << 4) + (lane >> 2);        // K row 0..63
    const int kcb = (lane & 3) << 4;                // K col byte
    const int vrw = (wv << 3) + (lane >> 3);        // V row 0..31
    const int vcb = (lane & 7) << 4;                // V col byte
    const size_t ksrc0 = ((size_t)krw << 6) + (size_t)(kcb ^ ((krw & 3) << 4));
    const size_t vsrc0 = ((size_t)vrw << 10) + (size_t)(vcb ^ ((vrw & 7) << 4));

    bf16x8 aq = *reinterpret_cast<const bf16x8*>(qbase + (q0 + c15) * HDn + kof);

    const float NML = -12.f * 1.4426950408889634f;   // -M*log2e, folded into QK^T C
    const float LOG2E = 1.4426950408889634f;
    const f32x4 zML = {NML, NML, NML, NML};
    f32x4 o[2] = {};
    f32x4 lsv = {0.f, 0.f, 0.f, 0.f};

    // ---- prologue: stage chunk 0 -> LDS buf 0 ----
    gl_lds16((const char*)kbase + ksrc0, (char*)kvlds[0] + wv * 1024);
    gl_lds16((const char*)vbase + vsrc0, (char*)kvlds[0] + 4096 + wv * 1024);

    #pragma unroll 1
    for (int c = 0; c < 8; c++) {         // 8 chunks of 64 k-cols
        const int pb = c & 1;
        // ---- bias/nbias tiled loads: 8 coalesced dwordx4 (newest VMEM) ----
        f32x4 bt[4], nt_[4];
        #pragma unroll
        for (int t = 0; t < 4; t++) {
            bt[t]  = *reinterpret_cast<const f32x4*>(btb + c * 1024 + t * 256);
            nt_[t] = *reinterpret_cast<const f32x4*>(ntb + c * 1024 + t * 256);
        }
        // ---- counted drain: kill stage(c) [2 oldest], keep bias [8] ----
        __builtin_amdgcn_sched_barrier(0);
        asm volatile("s_waitcnt vmcnt(8)" ::: "memory");
        __builtin_amdgcn_s_barrier();
        __builtin_amdgcn_sched_barrier(0);
        // ---- issue stage(c+1) into the other buffer (safe: post-barrier) --
        if (c < 7) {
            char* dstb = (char*)kvlds[pb ^ 1] + wv * 1024;
            gl_lds16((const char*)kbase + (size_t)((c + 1) << 12) + ksrc0, dstb);
            gl_lds16((const char*)vbase + (size_t)((c + 1) << 7) + vsrc0, dstb + 4096);
        }
        // ---- QK^T from LDS K tile (swizzled read) ----
        const char* kl = (const char*)kvlds[pb];
        f32x4 sc[4];
        #pragma unroll
        for (int t = 0; t < 4; t++) {
            int kr = t * 16 + c15;
            bf16x8 kf = *reinterpret_cast<const bf16x8*>(kl + (kr << 6) + ((rgrp << 4) ^ ((kr & 3) << 4)));
            sc[t] = __builtin_amdgcn_mfma_f32_16x16x32_bf16(kf, aq, zML, 0, 0, 0);
        }
        // ---- softmax: e = exp2(fma(bb, L, sc)); pack P via cvt_pk ----
        f32x4 es[4];
        #pragma unroll
        for (int t = 0; t < 4; t++) {
            f32x4 bb = bt[t] + nt_[t];
            #pragma unroll
            for (int r = 0; r < 4; r++)
                es[t][r] = __builtin_amdgcn_exp2f(fmaf(bb[r], LOG2E, sc[t][r]));
            lsv += es[t];
        }
        unsigned int pw[8];
        #pragma unroll
        for (int t = 0; t < 4; t++) {
            asm("v_cvt_pk_bf16_f32 %0, %1, %2" : "=v"(pw[t * 2 + 0]) : "v"(es[t][0]), "v"(es[t][1]));
            asm("v_cvt_pk_bf16_f32 %0, %1, %2" : "=v"(pw[t * 2 + 1]) : "v"(es[t][2]), "v"(es[t][3]));
        }
        u32x4 a0 = {pw[0], pw[1], pw[2], pw[3]};
        u32x4 a1 = {pw[4], pw[5], pw[6], pw[7]};
        bf16x8 pa0 = __builtin_bit_cast(bf16x8, a0);
        bf16x8 pa1 = __builtin_bit_cast(bf16x8, a1);
        // ---- PV from LDS V tile (swizzled read), P in-register ----
        #pragma unroll
        for (int sub = 0; sub < 2; sub++) {
            bf16x8 ap = sub == 0 ? pa0 : pa1;
            #pragma unroll
            for (int nt = 0; nt < 2; nt++) {
                int vr = nt * 16 + c15;
                bf16x8 bv = *reinterpret_cast<const bf16x8*>(kl + 4096 + (vr << 7)
                                + (((sub << 6) | (rgrp << 4)) ^ ((vr & 7) << 4)));
                o[nt] = __builtin_amdgcn_mfma_f32_16x16x32_bf16(ap, bv, o[nt], 0, 0, 0);
            }
        }
    }

    float lsum = (lsv[0] + lsv[1]) + (lsv[2] + lsv[3]);
    lsum += __shfl_xor(lsum, 16, 64);
    lsum += __shfl_xor(lsum, 32, 64);
    float linv[4];
    #pragma unroll
    for (int r = 0; r < 4; r++)
        linv[r] = 1.f / __shfl(lsum, rgrp * 4 + r, 64);

    // epilogue: normalize, gate, store wa as bf16 [B,Q,H*HD]
    const bf16_t* gptr = gateb + (size_t)(b * Hn + h) * Qn * HDn;
    bf16_t* wptr = wab + (size_t)b * Qn * 256;
    const int qg = q0 + rgrp * 4;
    #pragma unroll
    for (int nt = 0; nt < 2; nt++) {
        int d = nt * 16 + c15;
        #pragma unroll
        for (int r = 0; r < 4; r++) {
            float g = (float)gptr[(qg + r) * HDn + d];
            wptr[(qg + r) * 256 + h * 32 + d] = tob(o[nt][r] * linv[r] * g);
        }
    }
}

// ---------------- output projection + bias ----------------
__global__ __launch_bounds__(256) void outproj_kernel(
    const bf16_t* __restrict__ wab, const bf16_t* __restrict__ wto,
    const float* __restrict__ outb, float* __restrict__ out)
{
    __shared__ bf16_t alds[64 * ALDS_STRIDE];
    const int m0 = blockIdx.x * 64;
    const int tid = threadIdx.x;
    const int lane = tid & 63;
    const int w = tid >> 6;
    const int ncb = w * 64;
    const int c15 = lane & 15;
    const int rgrp = lane >> 4;
    const int kof = rgrp * 8;

    #pragma unroll
    for (int i = 0; i < 8; i++) {
        int u = tid + i * 256;
        int row = u >> 5;
        int c16 = u & 31;
        bf16x8 a8 = *reinterpret_cast<const bf16x8*>(wab + (size_t)(m0 + row) * 256 + c16 * 8);
        *reinterpret_cast<bf16x8*>(&alds[row * ALDS_STRIDE + c16 * 8]) = a8;
    }
    __syncthreads();

    const bf16_t* wbase = wto + (size_t)(ncb >> 4) * 8 * 512 + lane * 8;
    f32x4 acc[4][4] = {};
    #pragma unroll
    for (int kc = 0; kc < 8; kc++) {
        bf16x8 am[4], bn[4];
        #pragma unroll
        for (int i = 0; i < 4; i++)
            am[i] = *reinterpret_cast<const bf16x8*>(&alds[(i * 16 + c15) * ALDS_STRIDE + kc * 32 + kof]);
        #pragma unroll
        for (int j = 0; j < 4; j++)
            bn[j] = *reinterpret_cast<const bf16x8*>(wbase + ((size_t)j * 8 + kc) * 512);
        #pragma unroll
        for (int i = 0; i < 4; i++)
            #pragma unroll
            for (int j = 0; j < 4; j++)
                acc[i][j] = __builtin_amdgcn_mfma_f32_16x16x32_bf16(am[i], bn[j], acc[i][j], 0, 0, 0);
    }

    #pragma unroll
    for (int j = 0; j < 4; j++) {
        int n = ncb + j * 16 + c15;
        float ob = outb[n];
        #pragma unroll
        for (int i = 0; i < 4; i++) {
            #pragma unroll
            for (int r = 0; r < 4; r++) {
                int m = m0 + i * 16 + rgrp * 4 + r;
                out[(size_t)m * 256 + n] = acc[i][j][r] + ob;
            }
        }
    }
}

extern "C" void kernel_launch(void* const* d_in, const int* in_sizes, int n_in,
                              void* d_out, int out_size, void* d_ws, size_t ws_size,
                              hipStream_t stream) {
    const float* q_data = (const float*)d_in[0];
    const float* m_data = (const float*)d_in[1];
    const float* bias = (const float*)d_in[2];
    const float* nbias = (const float*)d_in[3];
    const float* query_w = (const float*)d_in[4];
    const float* key_w = (const float*)d_in[5];
    const float* value_w = (const float*)d_in[6];
    const float* gating_w = (const float*)d_in[7];
    const float* gating_b = (const float*)d_in[8];
    const float* output_w = (const float*)d_in[9];
    const float* output_b = (const float*)d_in[10];
    float* out = (float*)d_out;

    char* ws = (char*)d_ws;
    const size_t WT = 256 * 256 * sizeof(bf16_t);
    const size_t PROJ = (size_t)Bb * Hn * Qn * HDn;      // bf16 elems
    bf16_t* wtq = (bf16_t*)(ws);
    bf16_t* wtk = (bf16_t*)(ws + WT);
    bf16_t* wtv = (bf16_t*)(ws + 2 * WT);
    bf16_t* wtg = (bf16_t*)(ws + 3 * WT);
    bf16_t* wto = (bf16_t*)(ws + 4 * WT);
    bf16_t* qb = (bf16_t*)(ws + 5 * WT);
    bf16_t* kb = qb + PROJ;
    bf16_t* vtb = kb + PROJ;
    bf16_t* gateb = vtb + PROJ;
    bf16_t* wab = gateb + PROJ;

    const size_t BASE = 5 * WT + 5 * PROJ * sizeof(bf16_t);
    const size_t BT_BYTES = (size_t)64 * 65536 * 16;     // 67.1 MB
    float* btile = (float*)(ws + BASE);
    float* ntile = (float*)(ws + BASE + BT_BYTES);

    prep_weights<<<1280, 256, 0, stream>>>(query_w, key_w, value_w, gating_w, output_w,
                                           wtq, wtk, wtv, wtg, wto);
    prep_bias<<<2304, 256, 0, stream>>>(bias, nbias, btile, ntile);
    proj_kernel<<<dim3(512, 2), 512, 0, stream>>>(q_data, m_data, wtq, wtk, wtv, wtg,
                                                  gating_b, qb, kb, vtb, gateb);
    attn_kernel<<<4096, 256, 0, stream>>>(qb, kb, vtb, gateb, btile, ntile, wab);
    outproj_kernel<<<512, 256, 0, stream>>>(wab, wto, output_b, out);
}

// Round 13
// 169.301 us; speedup vs baseline: 1.1746x; 1.0133x over previous
//
#include <hip/hip_runtime.h>
#include <math.h>

#define Bb 64
#define Qn 512
#define Kn 512
#define Cn 256
#define Hn 8
#define HDn 32
#define OUTn 256

typedef __bf16 bf16_t;
typedef __attribute__((ext_vector_type(4))) __bf16 bf16x4;
typedef __attribute__((ext_vector_type(8))) __bf16 bf16x8;
typedef __attribute__((ext_vector_type(4))) float f32x4;
typedef __attribute__((ext_vector_type(4))) unsigned int u32x4;

__device__ inline bf16_t tob(float f) {
    unsigned int u = __float_as_uint(f);
    u += 0x7fff + ((u >> 16) & 1);   // RNE
    unsigned short s = (unsigned short)(u >> 16);
    return __builtin_bit_cast(bf16_t, s);
}

// async global->LDS, 16B per lane; LDS dest = wave-uniform base + lane*16
__device__ inline void gl_lds16(const void* g, void* l) {
    __builtin_amdgcn_global_load_lds(
        (const __attribute__((address_space(1))) unsigned int*)g,
        (__attribute__((address_space(3))) unsigned int*)l, 16, 0, 0);
}

// ---------------- weight prep: cast to bf16, MFMA-fragment-tiled ----------
// weights stored in the exact B-fragment order proj/outproj consume:
//   element (n, k) -> wt[ ((n>>4)*8 + (k>>5))*512 + lane*8 + (k&7) ],
//   lane = ((k>>3)&3)*16 + (n&15).
__global__ __launch_bounds__(256) void prep_weights(
    const float* __restrict__ qw, const float* __restrict__ kw,
    const float* __restrict__ vw, const float* __restrict__ gw,
    const float* __restrict__ ow,
    bf16_t* __restrict__ wtq, bf16_t* __restrict__ wtk,
    bf16_t* __restrict__ wtv, bf16_t* __restrict__ wtg,
    bf16_t* __restrict__ wto)
{
    int tid = blockIdx.x * 256 + threadIdx.x;   // 0 .. 5*65536-1
    int mat = tid >> 16;
    int rem = tid & 65535;
    int a = rem >> 8;    // source row (k dim)
    int n = rem & 255;   // source col (n dim)
    const float* src = mat == 0 ? qw : mat == 1 ? kw : mat == 2 ? vw : mat == 3 ? gw : ow;
    bf16_t* dst = mat == 0 ? wtq : mat == 1 ? wtk : mat == 2 ? wtv : mat == 3 ? wtg : wto;
    int nb = n >> 4, kb = a >> 5, rg = (a >> 3) & 3, e = a & 7, nl = n & 15;
    size_t idx = (((size_t)(nb * 8 + kb) * 64) + rg * 16 + nl) * 8 + e;
    dst[idx] = tob(src[a * 256 + n]);
}

// ---------------- fused projections + bias tiling (R13) -------------------
// R13 horizontal fusion: prep_bias has NO dependency on proj (btile/ntile
// feed only attn), and proj runs <25% on every pipe with ~2 blocks/CU --
// a machine full of idle slots. prep_bias's 2304 blocks ride in the same
// launch (blockIdx >= 1024, dispatched after proj's 1024), backfilling CU
// slots and hiding prep_bias's entire serial wall-clock slot (~15-25us).
// Branch is block-uniform (on blockIdx), so per-branch __syncthreads is
// legal. Shared LDS region: proj 40960B >= prep 33024B.
// proj part = R10 form (measured best 96us): R9 coalesced epilogue via
// LDS restage, R10 fragment-tiled weight loads, cvt_pk A-staging.
// R11 NOTE: halving tile doubled occupancy, ZERO speedup -> occupancy is
// not proj's binding resource; 64x64 tile retained.
#define ALDS_STRIDE 264   // 256 + 8 pad
__global__ __launch_bounds__(512) void proj_prep_kernel(
    const float* __restrict__ qdata, const float* __restrict__ mdata,
    const bf16_t* __restrict__ wtq, const bf16_t* __restrict__ wtk,
    const bf16_t* __restrict__ wtv, const bf16_t* __restrict__ wtg,
    const float* __restrict__ gating_b,
    bf16_t* __restrict__ qb, bf16_t* __restrict__ kb,
    bf16_t* __restrict__ vTb, bf16_t* __restrict__ gateb,
    const float* __restrict__ bias, const float* __restrict__ nbias,
    float* __restrict__ btile, float* __restrict__ ntile)
{
    __shared__ __align__(16) char smem_raw[40960];
    const int bid = blockIdx.x;
    const int tid = threadIdx.x;

    if (bid >= 1024) {
        // ---------------- prep_bias tile (R12 LDS transpose, 512 thd) -----
        float* tl = (float*)smem_raw;     // 16 x 516 f32 = 33024B
        const int pid = bid - 1024;       // 0..2303
        const bool isn = pid >= 2048;
        const int id2 = isn ? pid - 2048 : pid;   // (b or h)*32 + q16
        const int q16 = id2 & 31;
        const int bh = id2 >> 5;
        const float* src = (isn ? nbias : bias) + ((size_t)bh * Qn + q16 * 16) * Kn;
        float* dst = (isn ? ntile : btile) + ((size_t)id2 << 13);

        #pragma unroll
        for (int i = 0; i < 4; i++) {
            int u = tid + i * 512;        // 2048 f32x4 units
            int row = u >> 7;             // 0..15
            int c4 = u & 127;             // col/4
            f32x4 v = *reinterpret_cast<const f32x4*>(src + (size_t)row * Kn + c4 * 4);
            *reinterpret_cast<f32x4*>(&tl[row * 516 + c4 * 4]) = v;
        }
        __syncthreads();
        #pragma unroll
        for (int i = 0; i < 4; i++) {
            int u = tid + i * 512;        // out vec4 index within tile
            int lane = u & 63;
            int t = (u >> 6) & 3;
            int c = u >> 8;
            int row = lane & 15;
            int col = c * 64 + t * 16 + (lane >> 4) * 4;
            f32x4 v = *reinterpret_cast<const f32x4*>(&tl[row * 516 + col]);
            *reinterpret_cast<f32x4*>(dst + (size_t)u * 4) = v;
        }
        return;
    }

    // -------------------- proj (R10 form) ---------------------------------
    bf16_t* smem = (bf16_t*)smem_raw;     // A-tile (16896) / scratch (8x2560)
    bf16_t* alds = smem;
    const int side = bid >> 9;            // 0: q_data, 1: m_data
    const int m0 = (bid & 511) * 64;
    const int lane = tid & 63;
    const int w = tid >> 6;               // wave 0..7
    const int ch = w >> 2;                // 0: q|k, 1: gate|v
    const int ncb = (w & 3) * 64;
    const int c15 = lane & 15;
    const int rgrp = lane >> 4;
    const int kof = rgrp * 8;
    const float* X = side ? mdata : qdata;
    const bf16_t* Wt = side == 0 ? (ch == 0 ? wtq : wtg) : (ch == 0 ? wtk : wtv);
    const bool vout = (side == 1) && (ch == 1);

    #pragma unroll
    for (int i = 0; i < 8; i++) {
        int u = tid + i * 512;            // 4096 f32x4 units
        int row = u >> 6;
        int c4 = u & 63;
        f32x4 a4 = *reinterpret_cast<const f32x4*>(X + (size_t)(m0 + row) * 256 + c4 * 4);
        unsigned int p0, p1;
        asm("v_cvt_pk_bf16_f32 %0, %1, %2" : "=v"(p0) : "v"(a4[0]), "v"(a4[1]));
        asm("v_cvt_pk_bf16_f32 %0, %1, %2" : "=v"(p1) : "v"(a4[2]), "v"(a4[3]));
        unsigned long long pk = ((unsigned long long)p1 << 32) | p0;
        *reinterpret_cast<unsigned long long*>(&alds[row * ALDS_STRIDE + c4 * 4]) = pk;
    }
    __syncthreads();

    const bf16_t* wbase = Wt + (size_t)(ncb >> 4) * 8 * 512 + lane * 8;
    f32x4 acc[4][4] = {};
    #pragma unroll
    for (int kc = 0; kc < 8; kc++) {
        bf16x8 am[4], bn[4];
        #pragma unroll
        for (int i = 0; i < 4; i++)
            am[i] = *reinterpret_cast<const bf16x8*>(&alds[(i * 16 + c15) * ALDS_STRIDE + kc * 32 + kof]);
        #pragma unroll
        for (int j = 0; j < 4; j++)
            bn[j] = *reinterpret_cast<const bf16x8*>(wbase + ((size_t)j * 8 + kc) * 512);
        #pragma unroll
        for (int i = 0; i < 4; i++)
            #pragma unroll
            for (int j = 0; j < 4; j++) {
                if (vout)
                    acc[i][j] = __builtin_amdgcn_mfma_f32_16x16x32_bf16(bn[j], am[i], acc[i][j], 0, 0, 0);
                else
                    acc[i][j] = __builtin_amdgcn_mfma_f32_16x16x32_bf16(am[i], bn[j], acc[i][j], 0, 0, 0);
            }
    }

    __syncthreads();                      // all alds A-tile reads done; reuse as scratch
    bf16_t* scr = smem + w * 2560;        // per-wave slice, 16B-aligned

    // q is pre-scaled by log2(e)/sqrt(32): softmax computes exp2 directly.
    const float scale = 0.17677669529663687f * 1.4426950408889634f;
    const int hbase = ncb >> 5;
    const int posbase = m0 & 511;
    const int b = m0 >> 9;

    if (!vout) {
        bf16_t* dst = side == 0 ? (ch == 0 ? qb : gateb) : kb;
        #pragma unroll
        for (int P = 0; P < 2; P++) {
            // stage 2 i-slices (32 rows x 64 cols) -> scr[row][col], stride 72
            #pragma unroll
            for (int ii = 0; ii < 2; ii++) {
                int i = P * 2 + ii;
                #pragma unroll
                for (int j = 0; j < 4; j++) {
                    int n = ncb + j * 16 + c15;
                    #pragma unroll
                    for (int r = 0; r < 4; r++) {
                        float v = acc[i][j][r];
                        if (side == 0) {
                            if (ch == 0) v *= scale;
                            else v = 1.f / (1.f + __expf(-(v + gating_b[n])));
                        }
                        scr[(ii * 16 + rgrp * 4 + r) * 72 + j * 16 + c15] = tob(v);
                    }
                }
            }
            asm volatile("" ::: "memory");
            // coalesced write-out: 4 iters x 16B/lane, full 64B lines/instr
            #pragma unroll
            for (int v2 = 0; v2 < 4; v2++) {
                int row = v2 * 8 + (lane >> 3);
                int col = (lane & 7) * 8;
                bf16x8 val = *reinterpret_cast<const bf16x8*>(&scr[row * 72 + col]);
                int pos = posbase + P * 32 + row;
                int hh = hbase + (col >> 5);
                int d = col & 31;
                *reinterpret_cast<bf16x8*>(dst + (((size_t)(b * Hn + hh) * Qn + pos) << 5) + d) = val;
            }
            asm volatile("" ::: "memory");   // pass1 writes after pass0 reads
        }
    } else {
        // transposed acc: lanes index m-rows (key positions), regs index n=(h,d)
        // kk perm folded into the LDS WRITE column; readback is stride-1 in kk.
        #pragma unroll
        for (int P = 0; P < 2; P++) {
            #pragma unroll
            for (int ii = 0; ii < 2; ii++) {
                int i = P * 2 + ii;
                int kperm = (((c15 >> 3) & 1) << 4) | (((c15 >> 2) & 1) << 3) | (ii << 2)
                          | (((c15 >> 1) & 1) << 1) | (c15 & 1);
                #pragma unroll
                for (int j = 0; j < 4; j++)
                    #pragma unroll
                    for (int r = 0; r < 4; r++)
                        scr[(j * 16 + rgrp * 4 + r) * 40 + kperm] = tob(acc[i][j][r]);
            }
            asm volatile("" ::: "memory");
            #pragma unroll
            for (int u = 0; u < 4; u++) {
                int nloc = u * 16 + (lane >> 2);
                int koff = (lane & 3) * 8;
                bf16x8 val = *reinterpret_cast<const bf16x8*>(&scr[nloc * 40 + koff]);
                int hh = hbase + (nloc >> 5);
                int d = nloc & 31;
                *reinterpret_cast<bf16x8*>(vTb + ((size_t)(b * Hn + hh) * HDn + d) * Kn
                                           + posbase + P * 32 + koff) = val;
            }
            asm volatile("" ::: "memory");
        }
    }
}

// ---------------- fused attention, TILED-BIAS (R8, unchanged) -------------
// bias/nbias pre-tiled to fragment layout -> 8 coalesced dwordx4 per chunk
// straight to registers. LDS = 16KB kv dbuf only. Counted vmcnt(8): at the
// wait, outstanding = stage(c)[2 oldest] + bias(c)[8 newer].
__global__ __launch_bounds__(256) void attn_kernel(
    const bf16_t* __restrict__ qb, const bf16_t* __restrict__ kb,
    const bf16_t* __restrict__ vTb, const bf16_t* __restrict__ gateb,
    const float* __restrict__ btile, const float* __restrict__ ntile,
    bf16_t* __restrict__ wab)
{
    __shared__ __align__(16) char kvlds[2][8192];    // [buf][K 4KB | V 4KB]
    const int p = blockIdx.x;
    const int qt = p & 7;
    const int h = (p >> 3) & 7;
    const int b = p >> 6;
    const int lane = threadIdx.x & 63;
    const int wv = threadIdx.x >> 6;
    const int q0 = qt * 64 + wv * 16;
    const int q16 = qt * 4 + wv;
    const int c15 = lane & 15;
    const int rgrp = lane >> 4;
    const int kof = rgrp * 8;

    const bf16_t* qbase = qb + (size_t)(b * Hn + h) * Qn * HDn;
    const bf16_t* kbase = kb + (size_t)(b * Hn + h) * Kn * HDn;
    const bf16_t* vbase = vTb + (size_t)(b * Hn + h) * HDn * Kn;
    const float* btb = btile + (((size_t)b * 32 + q16) << 13) + lane * 4;   // 8192 f/q16
    const float* ntb = ntile + (((size_t)h * 32 + q16) << 13) + lane * 4;

    // staging lane geometry (constant per thread)
    const int krw = (wv << 4) + (lane >> 2);        // K row 0..63
    const int kcb = (lane & 3) << 4;                // K col byte
    const int vrw = (wv << 3) + (lane >> 3);        // V row 0..31
    const int vcb = (lane & 7) << 4;                // V col byte
    const size_t ksrc0 = ((size_t)krw << 6) + (size_t)(kcb ^ ((krw & 3) << 4));
    const size_t vsrc0 = ((size_t)vrw << 10) + (size_t)(vcb ^ ((vrw & 7) << 4));

    bf16x8 aq = *reinterpret_cast<const bf16x8*>(qbase + (q0 + c15) * HDn + kof);

    const float NML = -12.f * 1.4426950408889634f;   // -M*log2e, folded into QK^T C
    const float LOG2E = 1.4426950408889634f;
    const f32x4 zML = {NML, NML, NML, NML};
    f32x4 o[2] = {};
    f32x4 lsv = {0.f, 0.f, 0.f, 0.f};

    // ---- prologue: stage chunk 0 -> LDS buf 0 ----
    gl_lds16((const char*)kbase + ksrc0, (char*)kvlds[0] + wv * 1024);
    gl_lds16((const char*)vbase + vsrc0, (char*)kvlds[0] + 4096 + wv * 1024);

    #pragma unroll 1
    for (int c = 0; c < 8; c++) {         // 8 chunks of 64 k-cols
        const int pb = c & 1;
        // ---- bias/nbias tiled loads: 8 coalesced dwordx4 (newest VMEM) ----
        f32x4 bt[4], nt_[4];
        #pragma unroll
        for (int t = 0; t < 4; t++) {
            bt[t]  = *reinterpret_cast<const f32x4*>(btb + c * 1024 + t * 256);
            nt_[t] = *reinterpret_cast<const f32x4*>(ntb + c * 1024 + t * 256);
        }
        // ---- counted drain: kill stage(c) [2 oldest], keep bias [8] ----
        __builtin_amdgcn_sched_barrier(0);
        asm volatile("s_waitcnt vmcnt(8)" ::: "memory");
        __builtin_amdgcn_s_barrier();
        __builtin_amdgcn_sched_barrier(0);
        // ---- issue stage(c+1) into the other buffer (safe: post-barrier) --
        if (c < 7) {
            char* dstb = (char*)kvlds[pb ^ 1] + wv * 1024;
            gl_lds16((const char*)kbase + (size_t)((c + 1) << 12) + ksrc0, dstb);
            gl_lds16((const char*)vbase + (size_t)((c + 1) << 7) + vsrc0, dstb + 4096);
        }
        // ---- QK^T from LDS K tile (swizzled read) ----
        const char* kl = (const char*)kvlds[pb];
        f32x4 sc[4];
        #pragma unroll
        for (int t = 0; t < 4; t++) {
            int kr = t * 16 + c15;
            bf16x8 kf = *reinterpret_cast<const bf16x8*>(kl + (kr << 6) + ((rgrp << 4) ^ ((kr & 3) << 4)));
            sc[t] = __builtin_amdgcn_mfma_f32_16x16x32_bf16(kf, aq, zML, 0, 0, 0);
        }
        // ---- softmax: e = exp2(fma(bb, L, sc)); pack P via cvt_pk ----
        f32x4 es[4];
        #pragma unroll
        for (int t = 0; t < 4; t++) {
            f32x4 bb = bt[t] + nt_[t];
            #pragma unroll
            for (int r = 0; r < 4; r++)
                es[t][r] = __builtin_amdgcn_exp2f(fmaf(bb[r], LOG2E, sc[t][r]));
            lsv += es[t];
        }
        unsigned int pw[8];
        #pragma unroll
        for (int t = 0; t < 4; t++) {
            asm("v_cvt_pk_bf16_f32 %0, %1, %2" : "=v"(pw[t * 2 + 0]) : "v"(es[t][0]), "v"(es[t][1]));
            asm("v_cvt_pk_bf16_f32 %0, %1, %2" : "=v"(pw[t * 2 + 1]) : "v"(es[t][2]), "v"(es[t][3]));
        }
        u32x4 a0 = {pw[0], pw[1], pw[2], pw[3]};
        u32x4 a1 = {pw[4], pw[5], pw[6], pw[7]};
        bf16x8 pa0 = __builtin_bit_cast(bf16x8, a0);
        bf16x8 pa1 = __builtin_bit_cast(bf16x8, a1);
        // ---- PV from LDS V tile (swizzled read), P in-register ----
        #pragma unroll
        for (int sub = 0; sub < 2; sub++) {
            bf16x8 ap = sub == 0 ? pa0 : pa1;
            #pragma unroll
            for (int nt = 0; nt < 2; nt++) {
                int vr = nt * 16 + c15;
                bf16x8 bv = *reinterpret_cast<const bf16x8*>(kl + 4096 + (vr << 7)
                                + (((sub << 6) | (rgrp << 4)) ^ ((vr & 7) << 4)));
                o[nt] = __builtin_amdgcn_mfma_f32_16x16x32_bf16(ap, bv, o[nt], 0, 0, 0);
            }
        }
    }

    float lsum = (lsv[0] + lsv[1]) + (lsv[2] + lsv[3]);
    lsum += __shfl_xor(lsum, 16, 64);
    lsum += __shfl_xor(lsum, 32, 64);
    float linv[4];
    #pragma unroll
    for (int r = 0; r < 4; r++)
        linv[r] = 1.f / __shfl(lsum, rgrp * 4 + r, 64);

    // epilogue: normalize, gate, store wa as bf16 [B,Q,H*HD]
    const bf16_t* gptr = gateb + (size_t)(b * Hn + h) * Qn * HDn;
    bf16_t* wptr = wab + (size_t)b * Qn * 256;
    const int qg = q0 + rgrp * 4;
    #pragma unroll
    for (int nt = 0; nt < 2; nt++) {
        int d = nt * 16 + c15;
        #pragma unroll
        for (int r = 0; r < 4; r++) {
            float g = (float)gptr[(qg + r) * HDn + d];
            wptr[(qg + r) * 256 + h * 32 + d] = tob(o[nt][r] * linv[r] * g);
        }
    }
}

// ---------------- output projection + bias ----------------
__global__ __launch_bounds__(256) void outproj_kernel(
    const bf16_t* __restrict__ wab, const bf16_t* __restrict__ wto,
    const float* __restrict__ outb, float* __restrict__ out)
{
    __shared__ bf16_t alds[64 * ALDS_STRIDE];
    const int m0 = blockIdx.x * 64;
    const int tid = threadIdx.x;
    const int lane = tid & 63;
    const int w = tid >> 6;
    const int ncb = w * 64;
    const int c15 = lane & 15;
    const int rgrp = lane >> 4;
    const int kof = rgrp * 8;

    #pragma unroll
    for (int i = 0; i < 8; i++) {
        int u = tid + i * 256;
        int row = u >> 5;
        int c16 = u & 31;
        bf16x8 a8 = *reinterpret_cast<const bf16x8*>(wab + (size_t)(m0 + row) * 256 + c16 * 8);
        *reinterpret_cast<bf16x8*>(&alds[row * ALDS_STRIDE + c16 * 8]) = a8;
    }
    __syncthreads();

    const bf16_t* wbase = wto + (size_t)(ncb >> 4) * 8 * 512 + lane * 8;
    f32x4 acc[4][4] = {};
    #pragma unroll
    for (int kc = 0; kc < 8; kc++) {
        bf16x8 am[4], bn[4];
        #pragma unroll
        for (int i = 0; i < 4; i++)
            am[i] = *reinterpret_cast<const bf16x8*>(&alds[(i * 16 + c15) * ALDS_STRIDE + kc * 32 + kof]);
        #pragma unroll
        for (int j = 0; j < 4; j++)
            bn[j] = *reinterpret_cast<const bf16x8*>(wbase + ((size_t)j * 8 + kc) * 512);
        #pragma unroll
        for (int i = 0; i < 4; i++)
            #pragma unroll
            for (int j = 0; j < 4; j++)
                acc[i][j] = __builtin_amdgcn_mfma_f32_16x16x32_bf16(am[i], bn[j], acc[i][j], 0, 0, 0);
    }

    #pragma unroll
    for (int j = 0; j < 4; j++) {
        int n = ncb + j * 16 + c15;
        float ob = outb[n];
        #pragma unroll
        for (int i = 0; i < 4; i++) {
            #pragma unroll
            for (int r = 0; r < 4; r++) {
                int m = m0 + i * 16 + rgrp * 4 + r;
                out[(size_t)m * 256 + n] = acc[i][j][r] + ob;
            }
        }
    }
}

extern "C" void kernel_launch(void* const* d_in, const int* in_sizes, int n_in,
                              void* d_out, int out_size, void* d_ws, size_t ws_size,
                              hipStream_t stream) {
    const float* q_data = (const float*)d_in[0];
    const float* m_data = (const float*)d_in[1];
    const float* bias = (const float*)d_in[2];
    const float* nbias = (const float*)d_in[3];
    const float* query_w = (const float*)d_in[4];
    const float* key_w = (const float*)d_in[5];
    const float* value_w = (const float*)d_in[6];
    const float* gating_w = (const float*)d_in[7];
    const float* gating_b = (const float*)d_in[8];
    const float* output_w = (const float*)d_in[9];
    const float* output_b = (const float*)d_in[10];
    float* out = (float*)d_out;

    char* ws = (char*)d_ws;
    const size_t WT = 256 * 256 * sizeof(bf16_t);
    const size_t PROJ = (size_t)Bb * Hn * Qn * HDn;      // bf16 elems
    bf16_t* wtq = (bf16_t*)(ws);
    bf16_t* wtk = (bf16_t*)(ws + WT);
    bf16_t* wtv = (bf16_t*)(ws + 2 * WT);
    bf16_t* wtg = (bf16_t*)(ws + 3 * WT);
    bf16_t* wto = (bf16_t*)(ws + 4 * WT);
    bf16_t* qb = (bf16_t*)(ws + 5 * WT);
    bf16_t* kb = qb + PROJ;
    bf16_t* vtb = kb + PROJ;
    bf16_t* gateb = vtb + PROJ;
    bf16_t* wab = gateb + PROJ;

    const size_t BASE = 5 * WT + 5 * PROJ * sizeof(bf16_t);
    const size_t BT_BYTES = (size_t)64 * 65536 * 16;     // 67.1 MB
    float* btile = (float*)(ws + BASE);
    float* ntile = (float*)(ws + BASE + BT_BYTES);

    prep_weights<<<1280, 256, 0, stream>>>(query_w, key_w, value_w, gating_w, output_w,
                                           wtq, wtk, wtv, wtg, wto);
    proj_prep_kernel<<<3328, 512, 0, stream>>>(q_data, m_data, wtq, wtk, wtv, wtg,
                                               gating_b, qb, kb, vtb, gateb,
                                               bias, nbias, btile, ntile);
    attn_kernel<<<4096, 256, 0, stream>>>(qb, kb, vtb, gateb, btile, ntile, wab);
    outproj_kernel<<<512, 256, 0, stream>>>(wab, wto, output_b, out);
}

// Round 14
// 161.681 us; speedup vs baseline: 1.2300x; 1.0471x over previous
//
#include <hip/hip_runtime.h>
#include <math.h>

#define Bb 64
#define Qn 512
#define Kn 512
#define Cn 256
#define Hn 8
#define HDn 32
#define OUTn 256

typedef __bf16 bf16_t;
typedef __attribute__((ext_vector_type(4))) __bf16 bf16x4;
typedef __attribute__((ext_vector_type(8))) __bf16 bf16x8;
typedef __attribute__((ext_vector_type(4))) float f32x4;
typedef __attribute__((ext_vector_type(4))) unsigned int u32x4;

__device__ inline bf16_t tob(float f) {
    unsigned int u = __float_as_uint(f);
    u += 0x7fff + ((u >> 16) & 1);   // RNE
    unsigned short s = (unsigned short)(u >> 16);
    return __builtin_bit_cast(bf16_t, s);
}

// async global->LDS, 16B per lane; LDS dest = wave-uniform base + lane*16
__device__ inline void gl_lds16(const void* g, void* l) {
    __builtin_amdgcn_global_load_lds(
        (const __attribute__((address_space(1))) unsigned int*)g,
        (__attribute__((address_space(3))) unsigned int*)l, 16, 0, 0);
}

// ---------------- weight prep: cast to bf16, MFMA-fragment-tiled ----------
// weights stored in the exact B-fragment order proj/outproj consume:
//   element (n, k) -> wt[ ((n>>4)*8 + (k>>5))*512 + lane*8 + (k&7) ],
//   lane = ((k>>3)&3)*16 + (n&15).
__global__ __launch_bounds__(256) void prep_weights(
    const float* __restrict__ qw, const float* __restrict__ kw,
    const float* __restrict__ vw, const float* __restrict__ gw,
    const float* __restrict__ ow,
    bf16_t* __restrict__ wtq, bf16_t* __restrict__ wtk,
    bf16_t* __restrict__ wtv, bf16_t* __restrict__ wtg,
    bf16_t* __restrict__ wto)
{
    int tid = blockIdx.x * 256 + threadIdx.x;   // 0 .. 5*65536-1
    int mat = tid >> 16;
    int rem = tid & 65535;
    int a = rem >> 8;    // source row (k dim)
    int n = rem & 255;   // source col (n dim)
    const float* src = mat == 0 ? qw : mat == 1 ? kw : mat == 2 ? vw : mat == 3 ? gw : ow;
    bf16_t* dst = mat == 0 ? wtq : mat == 1 ? wtk : mat == 2 ? wtv : mat == 3 ? wtg : wto;
    int nb = n >> 4, kb = a >> 5, rg = (a >> 3) & 3, e = a & 7, nl = n & 15;
    size_t idx = (((size_t)(nb * 8 + kb) * 64) + rg * 16 + nl) * 8 + e;
    dst[idx] = tob(src[a * 256 + n]);
}

// ---------------- fused projections + bias tiling (R13/R14) ---------------
// R13 fused prep_bias into proj's launch but dispatched prep blocks AFTER
// proj blocks (bid>=1024) -> concatenation, not overlap (133us vs 98+37
// serial = only 2us saved). R14: fine-grain INTERLEAVE. 3328 = 13*256 and
// 1024:2304 = 4:9, so rem=bid%13: rem<4 -> proj (grp*4+rem, bijective
// 0..1023), else prep (grp*9+rem-4, bijective 0..2303). Every 13
// consecutive IDs = 4 proj + 9 prep -> each CU holds a mix from t=0;
// prep's 151MB of pure BW work hides in proj's idle memory slots (proj:
// 13% HBM, 5% MFMA, 8% VALU -- mostly-idle pipes).
// proj part = R10 form (measured best): R9 coalesced epilogue via LDS
// restage, R10 fragment-tiled weight loads, cvt_pk A-staging. R11: more
// occupancy is NOT proj's lever (falsified).
#define ALDS_STRIDE 264   // 256 + 8 pad
__global__ __launch_bounds__(512) void proj_prep_kernel(
    const float* __restrict__ qdata, const float* __restrict__ mdata,
    const bf16_t* __restrict__ wtq, const bf16_t* __restrict__ wtk,
    const bf16_t* __restrict__ wtv, const bf16_t* __restrict__ wtg,
    const float* __restrict__ gating_b,
    bf16_t* __restrict__ qb, bf16_t* __restrict__ kb,
    bf16_t* __restrict__ vTb, bf16_t* __restrict__ gateb,
    const float* __restrict__ bias, const float* __restrict__ nbias,
    float* __restrict__ btile, float* __restrict__ ntile)
{
    __shared__ __align__(16) char smem_raw[40960];
    const int bid = blockIdx.x;
    const int grp = bid / 13;
    const int rem = bid % 13;
    const int tid = threadIdx.x;

    if (rem >= 4) {
        // ---------------- prep_bias tile (R12 LDS transpose, 512 thd) -----
        float* tl = (float*)smem_raw;     // 16 x 516 f32 = 33024B
        const int pid = grp * 9 + (rem - 4);      // 0..2303
        const bool isn = pid >= 2048;
        const int id2 = isn ? pid - 2048 : pid;   // (b or h)*32 + q16
        const int q16 = id2 & 31;
        const int bh = id2 >> 5;
        const float* src = (isn ? nbias : bias) + ((size_t)bh * Qn + q16 * 16) * Kn;
        float* dst = (isn ? ntile : btile) + ((size_t)id2 << 13);

        #pragma unroll
        for (int i = 0; i < 4; i++) {
            int u = tid + i * 512;        // 2048 f32x4 units
            int row = u >> 7;             // 0..15
            int c4 = u & 127;             // col/4
            f32x4 v = *reinterpret_cast<const f32x4*>(src + (size_t)row * Kn + c4 * 4);
            *reinterpret_cast<f32x4*>(&tl[row * 516 + c4 * 4]) = v;
        }
        __syncthreads();
        #pragma unroll
        for (int i = 0; i < 4; i++) {
            int u = tid + i * 512;        // out vec4 index within tile
            int lane = u & 63;
            int t = (u >> 6) & 3;
            int c = u >> 8;
            int row = lane & 15;
            int col = c * 64 + t * 16 + (lane >> 4) * 4;
            f32x4 v = *reinterpret_cast<const f32x4*>(&tl[row * 516 + col]);
            *reinterpret_cast<f32x4*>(dst + (size_t)u * 4) = v;
        }
        return;
    }

    // -------------------- proj (R10 form) ---------------------------------
    bf16_t* smem = (bf16_t*)smem_raw;     // A-tile (16896) / scratch (8x2560)
    bf16_t* alds = smem;
    const int id = grp * 4 + rem;         // 0..1023
    const int side = id >> 9;             // 0: q_data, 1: m_data
    const int m0 = (id & 511) * 64;
    const int lane = tid & 63;
    const int w = tid >> 6;               // wave 0..7
    const int ch = w >> 2;                // 0: q|k, 1: gate|v
    const int ncb = (w & 3) * 64;
    const int c15 = lane & 15;
    const int rgrp = lane >> 4;
    const int kof = rgrp * 8;
    const float* X = side ? mdata : qdata;
    const bf16_t* Wt = side == 0 ? (ch == 0 ? wtq : wtg) : (ch == 0 ? wtk : wtv);
    const bool vout = (side == 1) && (ch == 1);

    #pragma unroll
    for (int i = 0; i < 8; i++) {
        int u = tid + i * 512;            // 4096 f32x4 units
        int row = u >> 6;
        int c4 = u & 63;
        f32x4 a4 = *reinterpret_cast<const f32x4*>(X + (size_t)(m0 + row) * 256 + c4 * 4);
        unsigned int p0, p1;
        asm("v_cvt_pk_bf16_f32 %0, %1, %2" : "=v"(p0) : "v"(a4[0]), "v"(a4[1]));
        asm("v_cvt_pk_bf16_f32 %0, %1, %2" : "=v"(p1) : "v"(a4[2]), "v"(a4[3]));
        unsigned long long pk = ((unsigned long long)p1 << 32) | p0;
        *reinterpret_cast<unsigned long long*>(&alds[row * ALDS_STRIDE + c4 * 4]) = pk;
    }
    __syncthreads();

    const bf16_t* wbase = Wt + (size_t)(ncb >> 4) * 8 * 512 + lane * 8;
    f32x4 acc[4][4] = {};
    #pragma unroll
    for (int kc = 0; kc < 8; kc++) {
        bf16x8 am[4], bn[4];
        #pragma unroll
        for (int i = 0; i < 4; i++)
            am[i] = *reinterpret_cast<const bf16x8*>(&alds[(i * 16 + c15) * ALDS_STRIDE + kc * 32 + kof]);
        #pragma unroll
        for (int j = 0; j < 4; j++)
            bn[j] = *reinterpret_cast<const bf16x8*>(wbase + ((size_t)j * 8 + kc) * 512);
        #pragma unroll
        for (int i = 0; i < 4; i++)
            #pragma unroll
            for (int j = 0; j < 4; j++) {
                if (vout)
                    acc[i][j] = __builtin_amdgcn_mfma_f32_16x16x32_bf16(bn[j], am[i], acc[i][j], 0, 0, 0);
                else
                    acc[i][j] = __builtin_amdgcn_mfma_f32_16x16x32_bf16(am[i], bn[j], acc[i][j], 0, 0, 0);
            }
    }

    __syncthreads();                      // all alds A-tile reads done; reuse as scratch
    bf16_t* scr = smem + w * 2560;        // per-wave slice, 16B-aligned

    // q is pre-scaled by log2(e)/sqrt(32): softmax computes exp2 directly.
    const float scale = 0.17677669529663687f * 1.4426950408889634f;
    const int hbase = ncb >> 5;
    const int posbase = m0 & 511;
    const int b = m0 >> 9;

    if (!vout) {
        bf16_t* dst = side == 0 ? (ch == 0 ? qb : gateb) : kb;
        #pragma unroll
        for (int P = 0; P < 2; P++) {
            // stage 2 i-slices (32 rows x 64 cols) -> scr[row][col], stride 72
            #pragma unroll
            for (int ii = 0; ii < 2; ii++) {
                int i = P * 2 + ii;
                #pragma unroll
                for (int j = 0; j < 4; j++) {
                    int n = ncb + j * 16 + c15;
                    #pragma unroll
                    for (int r = 0; r < 4; r++) {
                        float v = acc[i][j][r];
                        if (side == 0) {
                            if (ch == 0) v *= scale;
                            else v = 1.f / (1.f + __expf(-(v + gating_b[n])));
                        }
                        scr[(ii * 16 + rgrp * 4 + r) * 72 + j * 16 + c15] = tob(v);
                    }
                }
            }
            asm volatile("" ::: "memory");
            // coalesced write-out: 4 iters x 16B/lane, full 64B lines/instr
            #pragma unroll
            for (int v2 = 0; v2 < 4; v2++) {
                int row = v2 * 8 + (lane >> 3);
                int col = (lane & 7) * 8;
                bf16x8 val = *reinterpret_cast<const bf16x8*>(&scr[row * 72 + col]);
                int pos = posbase + P * 32 + row;
                int hh = hbase + (col >> 5);
                int d = col & 31;
                *reinterpret_cast<bf16x8*>(dst + (((size_t)(b * Hn + hh) * Qn + pos) << 5) + d) = val;
            }
            asm volatile("" ::: "memory");   // pass1 writes after pass0 reads
        }
    } else {
        // transposed acc: lanes index m-rows (key positions), regs index n=(h,d)
        // kk perm folded into the LDS WRITE column; readback is stride-1 in kk.
        #pragma unroll
        for (int P = 0; P < 2; P++) {
            #pragma unroll
            for (int ii = 0; ii < 2; ii++) {
                int i = P * 2 + ii;
                int kperm = (((c15 >> 3) & 1) << 4) | (((c15 >> 2) & 1) << 3) | (ii << 2)
                          | (((c15 >> 1) & 1) << 1) | (c15 & 1);
                #pragma unroll
                for (int j = 0; j < 4; j++)
                    #pragma unroll
                    for (int r = 0; r < 4; r++)
                        scr[(j * 16 + rgrp * 4 + r) * 40 + kperm] = tob(acc[i][j][r]);
            }
            asm volatile("" ::: "memory");
            #pragma unroll
            for (int u = 0; u < 4; u++) {
                int nloc = u * 16 + (lane >> 2);
                int koff = (lane & 3) * 8;
                bf16x8 val = *reinterpret_cast<const bf16x8*>(&scr[nloc * 40 + koff]);
                int hh = hbase + (nloc >> 5);
                int d = nloc & 31;
                *reinterpret_cast<bf16x8*>(vTb + ((size_t)(b * Hn + hh) * HDn + d) * Kn
                                           + posbase + P * 32 + koff) = val;
            }
            asm volatile("" ::: "memory");
        }
    }
}

// ---------------- fused attention, TILED-BIAS (R8, unchanged) -------------
// bias/nbias pre-tiled to fragment layout -> 8 coalesced dwordx4 per chunk
// straight to registers. LDS = 16KB kv dbuf only. Counted vmcnt(8): at the
// wait, outstanding = stage(c)[2 oldest] + bias(c)[8 newer].
__global__ __launch_bounds__(256) void attn_kernel(
    const bf16_t* __restrict__ qb, const bf16_t* __restrict__ kb,
    const bf16_t* __restrict__ vTb, const bf16_t* __restrict__ gateb,
    const float* __restrict__ btile, const float* __restrict__ ntile,
    bf16_t* __restrict__ wab)
{
    __shared__ __align__(16) char kvlds[2][8192];    // [buf][K 4KB | V 4KB]
    const int p = blockIdx.x;
    const int qt = p & 7;
    const int h = (p >> 3) & 7;
    const int b = p >> 6;
    const int lane = threadIdx.x & 63;
    const int wv = threadIdx.x >> 6;
    const int q0 = qt * 64 + wv * 16;
    const int q16 = qt * 4 + wv;
    const int c15 = lane & 15;
    const int rgrp = lane >> 4;
    const int kof = rgrp * 8;

    const bf16_t* qbase = qb + (size_t)(b * Hn + h) * Qn * HDn;
    const bf16_t* kbase = kb + (size_t)(b * Hn + h) * Kn * HDn;
    const bf16_t* vbase = vTb + (size_t)(b * Hn + h) * HDn * Kn;
    const float* btb = btile + (((size_t)b * 32 + q16) << 13) + lane * 4;   // 8192 f/q16
    const float* ntb = ntile + (((size_t)h * 32 + q16) << 13) + lane * 4;

    // staging lane geometry (constant per thread)
    const int krw = (wv << 4) + (lane >> 2);        // K row 0..63
    const int kcb = (lane & 3) << 4;                // K col byte
    const int vrw = (wv << 3) + (lane >> 3);        // V row 0..31
    const int vcb = (lane & 7) << 4;                // V col byte
    const size_t ksrc0 = ((size_t)krw << 6) + (size_t)(kcb ^ ((krw & 3) << 4));
    const size_t vsrc0 = ((size_t)vrw << 10) + (size_t)(vcb ^ ((vrw & 7) << 4));

    bf16x8 aq = *reinterpret_cast<const bf16x8*>(qbase + (q0 + c15) * HDn + kof);

    const float NML = -12.f * 1.4426950408889634f;   // -M*log2e, folded into QK^T C
    const float LOG2E = 1.4426950408889634f;
    const f32x4 zML = {NML, NML, NML, NML};
    f32x4 o[2] = {};
    f32x4 lsv = {0.f, 0.f, 0.f, 0.f};

    // ---- prologue: stage chunk 0 -> LDS buf 0 ----
    gl_lds16((const char*)kbase + ksrc0, (char*)kvlds[0] + wv * 1024);
    gl_lds16((const char*)vbase + vsrc0, (char*)kvlds[0] + 4096 + wv * 1024);

    #pragma unroll 1
    for (int c = 0; c < 8; c++) {         // 8 chunks of 64 k-cols
        const int pb = c & 1;
        // ---- bias/nbias tiled loads: 8 coalesced dwordx4 (newest VMEM) ----
        f32x4 bt[4], nt_[4];
        #pragma unroll
        for (int t = 0; t < 4; t++) {
            bt[t]  = *reinterpret_cast<const f32x4*>(btb + c * 1024 + t * 256);
            nt_[t] = *reinterpret_cast<const f32x4*>(ntb + c * 1024 + t * 256);
        }
        // ---- counted drain: kill stage(c) [2 oldest], keep bias [8] ----
        __builtin_amdgcn_sched_barrier(0);
        asm volatile("s_waitcnt vmcnt(8)" ::: "memory");
        __builtin_amdgcn_s_barrier();
        __builtin_amdgcn_sched_barrier(0);
        // ---- issue stage(c+1) into the other buffer (safe: post-barrier) --
        if (c < 7) {
            char* dstb = (char*)kvlds[pb ^ 1] + wv * 1024;
            gl_lds16((const char*)kbase + (size_t)((c + 1) << 12) + ksrc0, dstb);
            gl_lds16((const char*)vbase + (size_t)((c + 1) << 7) + vsrc0, dstb + 4096);
        }
        // ---- QK^T from LDS K tile (swizzled read) ----
        const char* kl = (const char*)kvlds[pb];
        f32x4 sc[4];
        #pragma unroll
        for (int t = 0; t < 4; t++) {
            int kr = t * 16 + c15;
            bf16x8 kf = *reinterpret_cast<const bf16x8*>(kl + (kr << 6) + ((rgrp << 4) ^ ((kr & 3) << 4)));
            sc[t] = __builtin_amdgcn_mfma_f32_16x16x32_bf16(kf, aq, zML, 0, 0, 0);
        }
        // ---- softmax: e = exp2(fma(bb, L, sc)); pack P via cvt_pk ----
        f32x4 es[4];
        #pragma unroll
        for (int t = 0; t < 4; t++) {
            f32x4 bb = bt[t] + nt_[t];
            #pragma unroll
            for (int r = 0; r < 4; r++)
                es[t][r] = __builtin_amdgcn_exp2f(fmaf(bb[r], LOG2E, sc[t][r]));
            lsv += es[t];
        }
        unsigned int pw[8];
        #pragma unroll
        for (int t = 0; t < 4; t++) {
            asm("v_cvt_pk_bf16_f32 %0, %1, %2" : "=v"(pw[t * 2 + 0]) : "v"(es[t][0]), "v"(es[t][1]));
            asm("v_cvt_pk_bf16_f32 %0, %1, %2" : "=v"(pw[t * 2 + 1]) : "v"(es[t][2]), "v"(es[t][3]));
        }
        u32x4 a0 = {pw[0], pw[1], pw[2], pw[3]};
        u32x4 a1 = {pw[4], pw[5], pw[6], pw[7]};
        bf16x8 pa0 = __builtin_bit_cast(bf16x8, a0);
        bf16x8 pa1 = __builtin_bit_cast(bf16x8, a1);
        // ---- PV from LDS V tile (swizzled read), P in-register ----
        #pragma unroll
        for (int sub = 0; sub < 2; sub++) {
            bf16x8 ap = sub == 0 ? pa0 : pa1;
            #pragma unroll
            for (int nt = 0; nt < 2; nt++) {
                int vr = nt * 16 + c15;
                bf16x8 bv = *reinterpret_cast<const bf16x8*>(kl + 4096 + (vr << 7)
                                + (((sub << 6) | (rgrp << 4)) ^ ((vr & 7) << 4)));
                o[nt] = __builtin_amdgcn_mfma_f32_16x16x32_bf16(ap, bv, o[nt], 0, 0, 0);
            }
        }
    }

    float lsum = (lsv[0] + lsv[1]) + (lsv[2] + lsv[3]);
    lsum += __shfl_xor(lsum, 16, 64);
    lsum += __shfl_xor(lsum, 32, 64);
    float linv[4];
    #pragma unroll
    for (int r = 0; r < 4; r++)
        linv[r] = 1.f / __shfl(lsum, rgrp * 4 + r, 64);

    // epilogue: normalize, gate, store wa as bf16 [B,Q,H*HD]
    const bf16_t* gptr = gateb + (size_t)(b * Hn + h) * Qn * HDn;
    bf16_t* wptr = wab + (size_t)b * Qn * 256;
    const int qg = q0 + rgrp * 4;
    #pragma unroll
    for (int nt = 0; nt < 2; nt++) {
        int d = nt * 16 + c15;
        #pragma unroll
        for (int r = 0; r < 4; r++) {
            float g = (float)gptr[(qg + r) * HDn + d];
            wptr[(qg + r) * 256 + h * 32 + d] = tob(o[nt][r] * linv[r] * g);
        }
    }
}

// ---------------- output projection + bias ----------------
__global__ __launch_bounds__(256) void outproj_kernel(
    const bf16_t* __restrict__ wab, const bf16_t* __restrict__ wto,
    const float* __restrict__ outb, float* __restrict__ out)
{
    __shared__ bf16_t alds[64 * ALDS_STRIDE];
    const int m0 = blockIdx.x * 64;
    const int tid = threadIdx.x;
    const int lane = tid & 63;
    const int w = tid >> 6;
    const int ncb = w * 64;
    const int c15 = lane & 15;
    const int rgrp = lane >> 4;
    const int kof = rgrp * 8;

    #pragma unroll
    for (int i = 0; i < 8; i++) {
        int u = tid + i * 256;
        int row = u >> 5;
        int c16 = u & 31;
        bf16x8 a8 = *reinterpret_cast<const bf16x8*>(wab + (size_t)(m0 + row) * 256 + c16 * 8);
        *reinterpret_cast<bf16x8*>(&alds[row * ALDS_STRIDE + c16 * 8]) = a8;
    }
    __syncthreads();

    const bf16_t* wbase = wto + (size_t)(ncb >> 4) * 8 * 512 + lane * 8;
    f32x4 acc[4][4] = {};
    #pragma unroll
    for (int kc = 0; kc < 8; kc++) {
        bf16x8 am[4], bn[4];
        #pragma unroll
        for (int i = 0; i < 4; i++)
            am[i] = *reinterpret_cast<const bf16x8*>(&alds[(i * 16 + c15) * ALDS_STRIDE + kc * 32 + kof]);
        #pragma unroll
        for (int j = 0; j < 4; j++)
            bn[j] = *reinterpret_cast<const bf16x8*>(wbase + ((size_t)j * 8 + kc) * 512);
        #pragma unroll
        for (int i = 0; i < 4; i++)
            #pragma unroll
            for (int j = 0; j < 4; j++)
                acc[i][j] = __builtin_amdgcn_mfma_f32_16x16x32_bf16(am[i], bn[j], acc[i][j], 0, 0, 0);
    }

    #pragma unroll
    for (int j = 0; j < 4; j++) {
        int n = ncb + j * 16 + c15;
        float ob = outb[n];
        #pragma unroll
        for (int i = 0; i < 4; i++) {
            #pragma unroll
            for (int r = 0; r < 4; r++) {
                int m = m0 + i * 16 + rgrp * 4 + r;
                out[(size_t)m * 256 + n] = acc[i][j][r] + ob;
            }
        }
    }
}

extern "C" void kernel_launch(void* const* d_in, const int* in_sizes, int n_in,
                              void* d_out, int out_size, void* d_ws, size_t ws_size,
                              hipStream_t stream) {
    const float* q_data = (const float*)d_in[0];
    const float* m_data = (const float*)d_in[1];
    const float* bias = (const float*)d_in[2];
    const float* nbias = (const float*)d_in[3];
    const float* query_w = (const float*)d_in[4];
    const float* key_w = (const float*)d_in[5];
    const float* value_w = (const float*)d_in[6];
    const float* gating_w = (const float*)d_in[7];
    const float* gating_b = (const float*)d_in[8];
    const float* output_w = (const float*)d_in[9];
    const float* output_b = (const float*)d_in[10];
    float* out = (float*)d_out;

    char* ws = (char*)d_ws;
    const size_t WT = 256 * 256 * sizeof(bf16_t);
    const size_t PROJ = (size_t)Bb * Hn * Qn * HDn;      // bf16 elems
    bf16_t* wtq = (bf16_t*)(ws);
    bf16_t* wtk = (bf16_t*)(ws + WT);
    bf16_t* wtv = (bf16_t*)(ws + 2 * WT);
    bf16_t* wtg = (bf16_t*)(ws + 3 * WT);
    bf16_t* wto = (bf16_t*)(ws + 4 * WT);
    bf16_t* qb = (bf16_t*)(ws + 5 * WT);
    bf16_t* kb = qb + PROJ;
    bf16_t* vtb = kb + PROJ;
    bf16_t* gateb = vtb + PROJ;
    bf16_t* wab = gateb + PROJ;

    const size_t BASE = 5 * WT + 5 * PROJ * sizeof(bf16_t);
    const size_t BT_BYTES = (size_t)64 * 65536 * 16;     // 67.1 MB
    float* btile = (float*)(ws + BASE);
    float* ntile = (float*)(ws + BASE + BT_BYTES);

    prep_weights<<<1280, 256, 0, stream>>>(query_w, key_w, value_w, gating_w, output_w,
                                           wtq, wtk, wtv, wtg, wto);
    proj_prep_kernel<<<3328, 512, 0, stream>>>(q_data, m_data, wtq, wtk, wtv, wtg,
                                               gating_b, qb, kb, vtb, gateb,
                                               bias, nbias, btile, ntile);
    attn_kernel<<<4096, 256, 0, stream>>>(qb, kb, vtb, gateb, btile, ntile, wab);
    outproj_kernel<<<512, 256, 0, stream>>>(wab, wto, output_b, out);
}

// Round 15
// 147.882 us; speedup vs baseline: 1.3447x; 1.0933x over previous
//
#include <hip/hip_runtime.h>
#include <math.h>

#define Bb 64
#define Qn 512
#define Kn 512
#define Cn 256
#define Hn 8
#define HDn 32
#define OUTn 256

typedef __bf16 bf16_t;
typedef _Float16 fp16_t;
typedef __attribute__((ext_vector_type(4))) __bf16 bf16x4;
typedef __attribute__((ext_vector_type(8))) __bf16 bf16x8;
typedef __attribute__((ext_vector_type(4))) _Float16 h16x4;
typedef __attribute__((ext_vector_type(8))) _Float16 h16x8;
typedef __attribute__((ext_vector_type(4))) float f32x4;
typedef __attribute__((ext_vector_type(4))) unsigned int u32x4;

__device__ inline bf16_t tob(float f) {
    unsigned int u = __float_as_uint(f);
    u += 0x7fff + ((u >> 16) & 1);   // RNE
    unsigned short s = (unsigned short)(u >> 16);
    return __builtin_bit_cast(bf16_t, s);
}

// async global->LDS, 16B per lane; LDS dest = wave-uniform base + lane*16
__device__ inline void gl_lds16(const void* g, void* l) {
    __builtin_amdgcn_global_load_lds(
        (const __attribute__((address_space(1))) unsigned int*)g,
        (__attribute__((address_space(3))) unsigned int*)l, 16, 0, 0);
}

// ---------------- weight prep: cast to bf16, MFMA-fragment-tiled ----------
// weights stored in the exact B-fragment order proj/outproj consume:
//   element (n, k) -> wt[ ((n>>4)*8 + (k>>5))*512 + lane*8 + (k&7) ],
//   lane = ((k>>3)&3)*16 + (n&15).
__global__ __launch_bounds__(256) void prep_weights(
    const float* __restrict__ qw, const float* __restrict__ kw,
    const float* __restrict__ vw, const float* __restrict__ gw,
    const float* __restrict__ ow,
    bf16_t* __restrict__ wtq, bf16_t* __restrict__ wtk,
    bf16_t* __restrict__ wtv, bf16_t* __restrict__ wtg,
    bf16_t* __restrict__ wto)
{
    int tid = blockIdx.x * 256 + threadIdx.x;   // 0 .. 5*65536-1
    int mat = tid >> 16;
    int rem = tid & 65535;
    int a = rem >> 8;    // source row (k dim)
    int n = rem & 255;   // source col (n dim)
    const float* src = mat == 0 ? qw : mat == 1 ? kw : mat == 2 ? vw : mat == 3 ? gw : ow;
    bf16_t* dst = mat == 0 ? wtq : mat == 1 ? wtk : mat == 2 ? wtv : mat == 3 ? wtg : wto;
    int nb = n >> 4, kb = a >> 5, rg = (a >> 3) & 3, e = a & 7, nl = n & 15;
    size_t idx = (((size_t)(nb * 8 + kb) * 64) + rg * 16 + nl) * 8 + e;
    dst[idx] = tob(src[a * 256 + n]);
}

// ---------------- fused projections + bias tiling (R13/R14/R15) -----------
// R14 interleave: rem=bid%13: rem<4 -> proj (4:9 ratio, bijective), else
// prep. Every 13 consecutive IDs = 4 proj + 9 prep -> CU-level overlap;
// fused incremental prep cost ~= prep's HBM-BW floor (overlap maxed).
// R15: bias tiles stored as FP16 pre-scaled by log2e. Budget analysis
// showed attn reads 1.05 GB of btile/ntile at L2 (btile[b] x8 h, ntile[h]
// x64 b) at ~35 TB/s ~= the L2 ceiling -> attn is bias-L2-BW-bound.
// fp16 halves that stream (and prep's write bytes). fp16 (10-bit mantissa,
// |L*bias|<~8) keeps worst-case logit err ~0.008 in the exp2 exponent.
// Tile layout (per (b|h, q16), 8192 fp16 = 16KB):
//   tile[c 8][lane 64][j 16], j = t*4+r,
//   value = LOG2E * bias[bh][q16*16+(lane&15)][c*64+t*16+(lane>>4)*4+r]
// proj part = R10 form (measured best). R11: occupancy NOT proj's lever.
#define ALDS_STRIDE 264   // 256 + 8 pad
__global__ __launch_bounds__(512) void proj_prep_kernel(
    const float* __restrict__ qdata, const float* __restrict__ mdata,
    const bf16_t* __restrict__ wtq, const bf16_t* __restrict__ wtk,
    const bf16_t* __restrict__ wtv, const bf16_t* __restrict__ wtg,
    const float* __restrict__ gating_b,
    bf16_t* __restrict__ qb, bf16_t* __restrict__ kb,
    bf16_t* __restrict__ vTb, bf16_t* __restrict__ gateb,
    const float* __restrict__ bias, const float* __restrict__ nbias,
    float* __restrict__ btile, float* __restrict__ ntile)
{
    __shared__ __align__(16) char smem_raw[40960];
    const int bid = blockIdx.x;
    const int grp = bid / 13;
    const int rem = bid % 13;
    const int tid = threadIdx.x;

    if (rem >= 4) {
        // ---------------- prep_bias tile (LDS transpose -> fp16 out) ------
        float* tl = (float*)smem_raw;     // 16 x 516 f32 = 33024B
        const int pid = grp * 9 + (rem - 4);      // 0..2303
        const bool isn = pid >= 2048;
        const int id2 = isn ? pid - 2048 : pid;   // (b or h)*32 + q16
        const int q16 = id2 & 31;
        const int bh = id2 >> 5;
        const float* src = (isn ? nbias : bias) + ((size_t)bh * Qn + q16 * 16) * Kn;
        fp16_t* dst = (fp16_t*)(isn ? ntile : btile) + ((size_t)id2 << 13);
        const float L = 1.4426950408889634f;

        #pragma unroll
        for (int i = 0; i < 4; i++) {
            int u = tid + i * 512;        // 2048 f32x4 units
            int row = u >> 7;             // 0..15
            int c4 = u & 127;             // col/4
            f32x4 v = *reinterpret_cast<const f32x4*>(src + (size_t)row * Kn + c4 * 4);
            *reinterpret_cast<f32x4*>(&tl[row * 516 + c4 * 4]) = v;
        }
        __syncthreads();
        #pragma unroll
        for (int i = 0; i < 4; i++) {
            int u = tid + i * 512;        // (c, lane, t), t fastest
            int t = u & 3;
            int lane = (u >> 2) & 63;
            int c = u >> 8;
            int row = lane & 15;
            int col = c * 64 + t * 16 + ((lane >> 4) << 2);
            f32x4 v = *reinterpret_cast<const f32x4*>(&tl[row * 516 + col]);
            h16x4 hv;
            #pragma unroll
            for (int k = 0; k < 4; k++) hv[k] = (fp16_t)(v[k] * L);
            *reinterpret_cast<h16x4*>(dst + c * 1024 + lane * 16 + t * 4) = hv;
        }
        return;
    }

    // -------------------- proj (R10 form) ---------------------------------
    bf16_t* smem = (bf16_t*)smem_raw;     // A-tile (16896) / scratch (8x2560)
    bf16_t* alds = smem;
    const int id = grp * 4 + rem;         // 0..1023
    const int side = id >> 9;             // 0: q_data, 1: m_data
    const int m0 = (id & 511) * 64;
    const int lane = tid & 63;
    const int w = tid >> 6;               // wave 0..7
    const int ch = w >> 2;                // 0: q|k, 1: gate|v
    const int ncb = (w & 3) * 64;
    const int c15 = lane & 15;
    const int rgrp = lane >> 4;
    const int kof = rgrp * 8;
    const float* X = side ? mdata : qdata;
    const bf16_t* Wt = side == 0 ? (ch == 0 ? wtq : wtg) : (ch == 0 ? wtk : wtv);
    const bool vout = (side == 1) && (ch == 1);

    #pragma unroll
    for (int i = 0; i < 8; i++) {
        int u = tid + i * 512;            // 4096 f32x4 units
        int row = u >> 6;
        int c4 = u & 63;
        f32x4 a4 = *reinterpret_cast<const f32x4*>(X + (size_t)(m0 + row) * 256 + c4 * 4);
        unsigned int p0, p1;
        asm("v_cvt_pk_bf16_f32 %0, %1, %2" : "=v"(p0) : "v"(a4[0]), "v"(a4[1]));
        asm("v_cvt_pk_bf16_f32 %0, %1, %2" : "=v"(p1) : "v"(a4[2]), "v"(a4[3]));
        unsigned long long pk = ((unsigned long long)p1 << 32) | p0;
        *reinterpret_cast<unsigned long long*>(&alds[row * ALDS_STRIDE + c4 * 4]) = pk;
    }
    __syncthreads();

    const bf16_t* wbase = Wt + (size_t)(ncb >> 4) * 8 * 512 + lane * 8;
    f32x4 acc[4][4] = {};
    #pragma unroll
    for (int kc = 0; kc < 8; kc++) {
        bf16x8 am[4], bn[4];
        #pragma unroll
        for (int i = 0; i < 4; i++)
            am[i] = *reinterpret_cast<const bf16x8*>(&alds[(i * 16 + c15) * ALDS_STRIDE + kc * 32 + kof]);
        #pragma unroll
        for (int j = 0; j < 4; j++)
            bn[j] = *reinterpret_cast<const bf16x8*>(wbase + ((size_t)j * 8 + kc) * 512);
        #pragma unroll
        for (int i = 0; i < 4; i++)
            #pragma unroll
            for (int j = 0; j < 4; j++) {
                if (vout)
                    acc[i][j] = __builtin_amdgcn_mfma_f32_16x16x32_bf16(bn[j], am[i], acc[i][j], 0, 0, 0);
                else
                    acc[i][j] = __builtin_amdgcn_mfma_f32_16x16x32_bf16(am[i], bn[j], acc[i][j], 0, 0, 0);
            }
    }

    __syncthreads();                      // all alds A-tile reads done; reuse as scratch
    bf16_t* scr = smem + w * 2560;        // per-wave slice, 16B-aligned

    // q is pre-scaled by log2(e)/sqrt(32): softmax computes exp2 directly.
    const float scale = 0.17677669529663687f * 1.4426950408889634f;
    const int hbase = ncb >> 5;
    const int posbase = m0 & 511;
    const int b = m0 >> 9;

    if (!vout) {
        bf16_t* dst = side == 0 ? (ch == 0 ? qb : gateb) : kb;
        #pragma unroll
        for (int P = 0; P < 2; P++) {
            // stage 2 i-slices (32 rows x 64 cols) -> scr[row][col], stride 72
            #pragma unroll
            for (int ii = 0; ii < 2; ii++) {
                int i = P * 2 + ii;
                #pragma unroll
                for (int j = 0; j < 4; j++) {
                    int n = ncb + j * 16 + c15;
                    #pragma unroll
                    for (int r = 0; r < 4; r++) {
                        float v = acc[i][j][r];
                        if (side == 0) {
                            if (ch == 0) v *= scale;
                            else v = 1.f / (1.f + __expf(-(v + gating_b[n])));
                        }
                        scr[(ii * 16 + rgrp * 4 + r) * 72 + j * 16 + c15] = tob(v);
                    }
                }
            }
            asm volatile("" ::: "memory");
            // coalesced write-out: 4 iters x 16B/lane, full 64B lines/instr
            #pragma unroll
            for (int v2 = 0; v2 < 4; v2++) {
                int row = v2 * 8 + (lane >> 3);
                int col = (lane & 7) * 8;
                bf16x8 val = *reinterpret_cast<const bf16x8*>(&scr[row * 72 + col]);
                int pos = posbase + P * 32 + row;
                int hh = hbase + (col >> 5);
                int d = col & 31;
                *reinterpret_cast<bf16x8*>(dst + (((size_t)(b * Hn + hh) * Qn + pos) << 5) + d) = val;
            }
            asm volatile("" ::: "memory");   // pass1 writes after pass0 reads
        }
    } else {
        // transposed acc: lanes index m-rows (key positions), regs index n=(h,d)
        // kk perm folded into the LDS WRITE column; readback is stride-1 in kk.
        #pragma unroll
        for (int P = 0; P < 2; P++) {
            #pragma unroll
            for (int ii = 0; ii < 2; ii++) {
                int i = P * 2 + ii;
                int kperm = (((c15 >> 3) & 1) << 4) | (((c15 >> 2) & 1) << 3) | (ii << 2)
                          | (((c15 >> 1) & 1) << 1) | (c15 & 1);
                #pragma unroll
                for (int j = 0; j < 4; j++)
                    #pragma unroll
                    for (int r = 0; r < 4; r++)
                        scr[(j * 16 + rgrp * 4 + r) * 40 + kperm] = tob(acc[i][j][r]);
            }
            asm volatile("" ::: "memory");
            #pragma unroll
            for (int u = 0; u < 4; u++) {
                int nloc = u * 16 + (lane >> 2);
                int koff = (lane & 3) * 8;
                bf16x8 val = *reinterpret_cast<const bf16x8*>(&scr[nloc * 40 + koff]);
                int hh = hbase + (nloc >> 5);
                int d = nloc & 31;
                *reinterpret_cast<bf16x8*>(vTb + ((size_t)(b * Hn + hh) * HDn + d) * Kn
                                           + posbase + P * 32 + koff) = val;
            }
            asm volatile("" ::: "memory");
        }
    }
}

// ---------------- fused attention, FP16-TILED-BIAS (R15) ------------------
// bias/nbias pre-tiled fp16 (pre-scaled by log2e) -> per chunk, 4 coalesced
// 16B loads (was 8; bytes halved -- attn was bias-L2-BW-bound at ~35 TB/s).
// LDS = 16KB kv dbuf only. Counted vmcnt(4): at the wait, outstanding =
// stage(c)[2 oldest] + bias(c)[4 newer].
__global__ __launch_bounds__(256) void attn_kernel(
    const bf16_t* __restrict__ qb, const bf16_t* __restrict__ kb,
    const bf16_t* __restrict__ vTb, const bf16_t* __restrict__ gateb,
    const float* __restrict__ btile, const float* __restrict__ ntile,
    bf16_t* __restrict__ wab)
{
    __shared__ __align__(16) char kvlds[2][8192];    // [buf][K 4KB | V 4KB]
    const int p = blockIdx.x;
    const int qt = p & 7;
    const int h = (p >> 3) & 7;
    const int b = p >> 6;
    const int lane = threadIdx.x & 63;
    const int wv = threadIdx.x >> 6;
    const int q0 = qt * 64 + wv * 16;
    const int q16 = qt * 4 + wv;
    const int c15 = lane & 15;
    const int rgrp = lane >> 4;
    const int kof = rgrp * 8;

    const bf16_t* qbase = qb + (size_t)(b * Hn + h) * Qn * HDn;
    const bf16_t* kbase = kb + (size_t)(b * Hn + h) * Kn * HDn;
    const bf16_t* vbase = vTb + (size_t)(b * Hn + h) * HDn * Kn;
    const fp16_t* btb = (const fp16_t*)btile + (((size_t)b * 32 + q16) << 13) + lane * 16;
    const fp16_t* ntb = (const fp16_t*)ntile + (((size_t)h * 32 + q16) << 13) + lane * 16;

    // staging lane geometry (constant per thread)
    const int krw = (wv << 4) + (lane >> 2);        // K row 0..63
    const int kcb = (lane & 3) << 4;                // K col byte
    const int vrw = (wv << 3) + (lane >> 3);        // V row 0..31
    const int vcb = (lane & 7) << 4;                // V col byte
    const size_t ksrc0 = ((size_t)krw << 6) + (size_t)(kcb ^ ((krw & 3) << 4));
    const size_t vsrc0 = ((size_t)vrw << 10) + (size_t)(vcb ^ ((vrw & 7) << 4));

    bf16x8 aq = *reinterpret_cast<const bf16x8*>(qbase + (q0 + c15) * HDn + kof);

    const float NML = -12.f * 1.4426950408889634f;   // -M*log2e, folded into QK^T C
    const f32x4 zML = {NML, NML, NML, NML};
    f32x4 o[2] = {};
    f32x4 lsv = {0.f, 0.f, 0.f, 0.f};

    // ---- prologue: stage chunk 0 -> LDS buf 0 ----
    gl_lds16((const char*)kbase + ksrc0, (char*)kvlds[0] + wv * 1024);
    gl_lds16((const char*)vbase + vsrc0, (char*)kvlds[0] + 4096 + wv * 1024);

    #pragma unroll 1
    for (int c = 0; c < 8; c++) {         // 8 chunks of 64 k-cols
        const int pb = c & 1;
        // ---- bias/nbias fp16 tiled loads: 4 coalesced 16B (newest VMEM) ----
        h16x8 bt0 = *reinterpret_cast<const h16x8*>(btb + c * 1024);
        h16x8 bt1 = *reinterpret_cast<const h16x8*>(btb + c * 1024 + 8);
        h16x8 nt0 = *reinterpret_cast<const h16x8*>(ntb + c * 1024);
        h16x8 nt1 = *reinterpret_cast<const h16x8*>(ntb + c * 1024 + 8);
        // ---- counted drain: kill stage(c) [2 oldest], keep bias [4] ----
        __builtin_amdgcn_sched_barrier(0);
        asm volatile("s_waitcnt vmcnt(4)" ::: "memory");
        __builtin_amdgcn_s_barrier();
        __builtin_amdgcn_sched_barrier(0);
        // ---- issue stage(c+1) into the other buffer (safe: post-barrier) --
        if (c < 7) {
            char* dstb = (char*)kvlds[pb ^ 1] + wv * 1024;
            gl_lds16((const char*)kbase + (size_t)((c + 1) << 12) + ksrc0, dstb);
            gl_lds16((const char*)vbase + (size_t)((c + 1) << 7) + vsrc0, dstb + 4096);
        }
        // ---- QK^T from LDS K tile (swizzled read) ----
        const char* kl = (const char*)kvlds[pb];
        f32x4 sc[4];
        #pragma unroll
        for (int t = 0; t < 4; t++) {
            int kr = t * 16 + c15;
            bf16x8 kf = *reinterpret_cast<const bf16x8*>(kl + (kr << 6) + ((rgrp << 4) ^ ((kr & 3) << 4)));
            sc[t] = __builtin_amdgcn_mfma_f32_16x16x32_bf16(kf, aq, zML, 0, 0, 0);
        }
        // ---- softmax: e = exp2(sc + bb); bb from fp16 tiles; cvt_pk P ----
        f32x4 es[4];
        #pragma unroll
        for (int t = 0; t < 4; t++) {
            #pragma unroll
            for (int r = 0; r < 4; r++) {
                int j = (t & 1) * 4 + r;
                float bbv = (t < 2)
                    ? ((float)bt0[j] + (float)nt0[j])
                    : ((float)bt1[j] + (float)nt1[j]);
                es[t][r] = __builtin_amdgcn_exp2f(sc[t][r] + bbv);
            }
            lsv += es[t];
        }
        unsigned int pw[8];
        #pragma unroll
        for (int t = 0; t < 4; t++) {
            asm("v_cvt_pk_bf16_f32 %0, %1, %2" : "=v"(pw[t * 2 + 0]) : "v"(es[t][0]), "v"(es[t][1]));
            asm("v_cvt_pk_bf16_f32 %0, %1, %2" : "=v"(pw[t * 2 + 1]) : "v"(es[t][2]), "v"(es[t][3]));
        }
        u32x4 a0 = {pw[0], pw[1], pw[2], pw[3]};
        u32x4 a1 = {pw[4], pw[5], pw[6], pw[7]};
        bf16x8 pa0 = __builtin_bit_cast(bf16x8, a0);
        bf16x8 pa1 = __builtin_bit_cast(bf16x8, a1);
        // ---- PV from LDS V tile (swizzled read), P in-register ----
        #pragma unroll
        for (int sub = 0; sub < 2; sub++) {
            bf16x8 ap = sub == 0 ? pa0 : pa1;
            #pragma unroll
            for (int nt = 0; nt < 2; nt++) {
                int vr = nt * 16 + c15;
                bf16x8 bv = *reinterpret_cast<const bf16x8*>(kl + 4096 + (vr << 7)
                                + (((sub << 6) | (rgrp << 4)) ^ ((vr & 7) << 4)));
                o[nt] = __builtin_amdgcn_mfma_f32_16x16x32_bf16(ap, bv, o[nt], 0, 0, 0);
            }
        }
    }

    float lsum = (lsv[0] + lsv[1]) + (lsv[2] + lsv[3]);
    lsum += __shfl_xor(lsum, 16, 64);
    lsum += __shfl_xor(lsum, 32, 64);
    float linv[4];
    #pragma unroll
    for (int r = 0; r < 4; r++)
        linv[r] = 1.f / __shfl(lsum, rgrp * 4 + r, 64);

    // epilogue: normalize, gate, store wa as bf16 [B,Q,H*HD]
    const bf16_t* gptr = gateb + (size_t)(b * Hn + h) * Qn * HDn;
    bf16_t* wptr = wab + (size_t)b * Qn * 256;
    const int qg = q0 + rgrp * 4;
    #pragma unroll
    for (int nt = 0; nt < 2; nt++) {
        int d = nt * 16 + c15;
        #pragma unroll
        for (int r = 0; r < 4; r++) {
            float g = (float)gptr[(qg + r) * HDn + d];
            wptr[(qg + r) * 256 + h * 32 + d] = tob(o[nt][r] * linv[r] * g);
        }
    }
}

// ---------------- output projection + bias ----------------
__global__ __launch_bounds__(256) void outproj_kernel(
    const bf16_t* __restrict__ wab, const bf16_t* __restrict__ wto,
    const float* __restrict__ outb, float* __restrict__ out)
{
    __shared__ bf16_t alds[64 * ALDS_STRIDE];
    const int m0 = blockIdx.x * 64;
    const int tid = threadIdx.x;
    const int lane = tid & 63;
    const int w = tid >> 6;
    const int ncb = w * 64;
    const int c15 = lane & 15;
    const int rgrp = lane >> 4;
    const int kof = rgrp * 8;

    #pragma unroll
    for (int i = 0; i < 8; i++) {
        int u = tid + i * 256;
        int row = u >> 5;
        int c16 = u & 31;
        bf16x8 a8 = *reinterpret_cast<const bf16x8*>(wab + (size_t)(m0 + row) * 256 + c16 * 8);
        *reinterpret_cast<bf16x8*>(&alds[row * ALDS_STRIDE + c16 * 8]) = a8;
    }
    __syncthreads();

    const bf16_t* wbase = wto + (size_t)(ncb >> 4) * 8 * 512 + lane * 8;
    f32x4 acc[4][4] = {};
    #pragma unroll
    for (int kc = 0; kc < 8; kc++) {
        bf16x8 am[4], bn[4];
        #pragma unroll
        for (int i = 0; i < 4; i++)
            am[i] = *reinterpret_cast<const bf16x8*>(&alds[(i * 16 + c15) * ALDS_STRIDE + kc * 32 + kof]);
        #pragma unroll
        for (int j = 0; j < 4; j++)
            bn[j] = *reinterpret_cast<const bf16x8*>(wbase + ((size_t)j * 8 + kc) * 512);
        #pragma unroll
        for (int i = 0; i < 4; i++)
            #pragma unroll
            for (int j = 0; j < 4; j++)
                acc[i][j] = __builtin_amdgcn_mfma_f32_16x16x32_bf16(am[i], bn[j], acc[i][j], 0, 0, 0);
    }

    #pragma unroll
    for (int j = 0; j < 4; j++) {
        int n = ncb + j * 16 + c15;
        float ob = outb[n];
        #pragma unroll
        for (int i = 0; i < 4; i++) {
            #pragma unroll
            for (int r = 0; r < 4; r++) {
                int m = m0 + i * 16 + rgrp * 4 + r;
                out[(size_t)m * 256 + n] = acc[i][j][r] + ob;
            }
        }
    }
}

extern "C" void kernel_launch(void* const* d_in, const int* in_sizes, int n_in,
                              void* d_out, int out_size, void* d_ws, size_t ws_size,
                              hipStream_t stream) {
    const float* q_data = (const float*)d_in[0];
    const float* m_data = (const float*)d_in[1];
    const float* bias = (const float*)d_in[2];
    const float* nbias = (const float*)d_in[3];
    const float* query_w = (const float*)d_in[4];
    const float* key_w = (const float*)d_in[5];
    const float* value_w = (const float*)d_in[6];
    const float* gating_w = (const float*)d_in[7];
    const float* gating_b = (const float*)d_in[8];
    const float* output_w = (const float*)d_in[9];
    const float* output_b = (const float*)d_in[10];
    float* out = (float*)d_out;

    char* ws = (char*)d_ws;
    const size_t WT = 256 * 256 * sizeof(bf16_t);
    const size_t PROJ = (size_t)Bb * Hn * Qn * HDn;      // bf16 elems
    bf16_t* wtq = (bf16_t*)(ws);
    bf16_t* wtk = (bf16_t*)(ws + WT);
    bf16_t* wtv = (bf16_t*)(ws + 2 * WT);
    bf16_t* wtg = (bf16_t*)(ws + 3 * WT);
    bf16_t* wto = (bf16_t*)(ws + 4 * WT);
    bf16_t* qb = (bf16_t*)(ws + 5 * WT);
    bf16_t* kb = qb + PROJ;
    bf16_t* vtb = kb + PROJ;
    bf16_t* gateb = vtb + PROJ;
    bf16_t* wab = gateb + PROJ;

    const size_t BASE = 5 * WT + 5 * PROJ * sizeof(bf16_t);
    const size_t BT_BYTES = (size_t)64 * 32 * 8192 * 2;  // fp16 tiles, 33.5 MB
    float* btile = (float*)(ws + BASE);
    float* ntile = (float*)(ws + BASE + BT_BYTES);

    prep_weights<<<1280, 256, 0, stream>>>(query_w, key_w, value_w, gating_w, output_w,
                                           wtq, wtk, wtv, wtg, wto);
    proj_prep_kernel<<<3328, 512, 0, stream>>>(q_data, m_data, wtq, wtk, wtv, wtg,
                                               gating_b, qb, kb, vtb, gateb,
                                               bias, nbias, btile, ntile);
    attn_kernel<<<4096, 256, 0, stream>>>(qb, kb, vtb, gateb, btile, ntile, wab);
    outproj_kernel<<<512, 256, 0, stream>>>(wab, wto, output_b, out);
}